// Round 6
// baseline (1235.937 us; speedup 1.0000x reference)
//
#include <hip/hip_runtime.h>

// ---------------------------------------------------------------------------
// DeformableTransformerEncoderLayer on MI355X (gfx950)
// B=4, LQ=13294, DM=256, DFFN=1024, NL=4, NH=8, NP=4, HD=32
// M = 53176 rows, padded tiles to Mp = 53248 = 416*128.
// Round 6:
//  - sample_k: __launch_bounds__(256,4) caps VGPR at 128 (was 136 -> 2
//    waves/SIMD per the 128-VGPR occupancy cliff; now 4).
//  - SRC=0 GEMMs: 2-phase double-buffered global_load_lds (stage next K-step
//    before computing current; ONE barrier per K-step).
// Pipeline:
//   G1: value_h = bf16(src) @ WvT + bv        (head-major scatter epilogue)
//   G2: offaw   = bf16(src+pos) @ [Ws|Wa]T + [bs|ba]  (bf16 logits, N=384)
//   sample:     attn_bf = MSDeformAttn(value_h, offaw, refp)  (softmax inside)
//   G4: z(d_out) = src + attn_bf @ WoT + bo   (fp32 + resid)
//   LN1: x_bf <- LN(z)                        (bf16, overlays value_h)
//   2x { G5p: h = relu(x_bf @ W1T[p] + b1[p])     (h overlays offaw+attn)
//        G6p: z = resid + h @ W2T[:,p] (+b2 on p0; resid = x_bf on p0 else z) }
//   LN2: d_out = LN(z) in place
// Workspace ~97 MB.
// ---------------------------------------------------------------------------

#define LQn   13294
#define MREAL 53176
#define MP    53248
#define MT    416

typedef __attribute__((ext_vector_type(8))) short short8;
typedef __attribute__((ext_vector_type(4))) short short4v;
typedef __attribute__((ext_vector_type(4))) float f32x4;

__device__ __forceinline__ short f2bf(float f) {
    unsigned u = __float_as_uint(f);
    unsigned r = (u + 0x7FFFu + ((u >> 16) & 1u)) >> 16;  // RNE
    return (short)r;
}
__device__ __forceinline__ float bf2f(short b) {
    return __uint_as_float(((unsigned)(unsigned short)b) << 16);
}

#define GLOAD16(gp, lp)                                                        \
    __builtin_amdgcn_global_load_lds(                                          \
        (const __attribute__((address_space(1))) void*)(gp),                   \
        (__attribute__((address_space(3))) void*)(lp), 16, 0, 0)

// ---------------------------------------------------------------------------
__global__ __launch_bounds__(256) void transpose_w(const float* __restrict__ W,
                                                   short* __restrict__ WT,
                                                   int K, int N) {
    const int i = blockIdx.x * 256 + threadIdx.x;
    if (i >= K * N) return;
    const int n = i / K, k = i - n * K;
    WT[i] = f2bf(W[(size_t)k * N + n]);
}

__global__ void prep_small_k(const float* __restrict__ bs,
                             const float* __restrict__ ba,
                             float* __restrict__ bsa,
                             float* __restrict__ zerob) {
    const int t = threadIdx.x;
    if (t < 256) { bsa[t] = bs[t]; zerob[t] = 0.f; }
    else if (t < 384) bsa[t] = ba[t - 256];
}

// ---------------------------------------------------------------------------
// bf16 MFMA GEMM. 128x128 tile, BK=32, 4 waves, 16x16x32 MFMA.
// SRC: 0 = A bf16[M][K], dbuf global_load_lds staging (1 barrier/K-step);
//      1 = A fp32 (convert); 2 = A+A2 fp32 (q=src+pos)  (reg staging)
// EPI: 1 = bf16+bias; 2 = relu->bf16+bias; 3 = fp32+bias+fp32 resid;
//      4 = fp32+bias+bf16 resid; 5 = bf16+bias scattered head-major
// ---------------------------------------------------------------------------
template <int SRC>
__device__ __forceinline__ short8 lda8(const float* Af, const float* A2,
                                       size_t idx) {
    const float4 lo = *(const float4*)(Af + idx);
    const float4 hi = *(const float4*)(Af + idx + 4);
    float v[8] = {lo.x, lo.y, lo.z, lo.w, hi.x, hi.y, hi.z, hi.w};
    if constexpr (SRC == 2) {
        const float4 lo2 = *(const float4*)(A2 + idx);
        const float4 hi2 = *(const float4*)(A2 + idx + 4);
        v[0] += lo2.x; v[1] += lo2.y; v[2] += lo2.z; v[3] += lo2.w;
        v[4] += hi2.x; v[5] += hi2.y; v[6] += hi2.z; v[7] += hi2.w;
    }
    short8 r;
#pragma unroll
    for (int j = 0; j < 8; ++j) r[j] = f2bf(v[j]);
    return r;
}

template <int SRC, int EPI>
__global__ __launch_bounds__(256) void gemm_bt(const short* __restrict__ Ab,
                                               const float* __restrict__ Af,
                                               const float* __restrict__ A2,
                                               const short* __restrict__ BT,
                                               const float* __restrict__ bias,
                                               const void* resid,
                                               void* C,
                                               int M, int K, int N,
                                               int ldb, int ldc) {
    const int t = threadIdx.x;
    const int m0 = blockIdx.x * 128, n0 = blockIdx.y * 128;
    const int wid = t >> 6, lane = t & 63;
    const int wr = wid >> 1, wc = wid & 1;
    const int quad = lane >> 4, l16 = lane & 15;

    f32x4 acc[4][4];
#pragma unroll
    for (int i = 0; i < 4; ++i)
#pragma unroll
        for (int j = 0; j < 4; ++j) acc[i][j] = (f32x4){0.f, 0.f, 0.f, 0.f};

    if constexpr (SRC == 0) {
        // --- 2-phase double-buffered global_load_lds staging ---
        __shared__ short lA[2][128 * 32];
        __shared__ short lB[2][128 * 32];
        const int grow = wid * 32 + (lane >> 2);   // row this lane feeds
        const int gcol = (lane & 3) * 8;           // 16B within row
        auto stage = [&](int buf, int k0) {
            GLOAD16(Ab + (size_t)(m0 + grow) * K + k0 + gcol,
                    &lA[buf][(wid * 32) * 32]);
            GLOAD16(Ab + (size_t)(m0 + grow + 16) * K + k0 + gcol,
                    &lA[buf][(wid * 32 + 16) * 32]);
            GLOAD16(BT + (size_t)(n0 + grow) * ldb + k0 + gcol,
                    &lB[buf][(wid * 32) * 32]);
            GLOAD16(BT + (size_t)(n0 + grow + 16) * ldb + k0 + gcol,
                    &lB[buf][(wid * 32 + 16) * 32]);
        };
        stage(0, 0);
        __syncthreads();   // vmcnt(0) drained by compiler before barrier
        int cur = 0;
        for (int k0 = 0; k0 < K; k0 += 32) {
            if (k0 + 32 < K) stage(cur ^ 1, k0 + 32);  // in flight during MFMA
            short8 af[4], bfr[4];
#pragma unroll
            for (int mi = 0; mi < 4; ++mi)
                af[mi] = *(const short8*)&lA[cur][(wr * 64 + mi * 16 + l16) * 32 + quad * 8];
#pragma unroll
            for (int ni = 0; ni < 4; ++ni)
                bfr[ni] = *(const short8*)&lB[cur][(wc * 64 + ni * 16 + l16) * 32 + quad * 8];
#pragma unroll
            for (int mi = 0; mi < 4; ++mi)
#pragma unroll
                for (int ni = 0; ni < 4; ++ni)
                    acc[mi][ni] = __builtin_amdgcn_mfma_f32_16x16x32_bf16(
                        af[mi], bfr[ni], acc[mi][ni], 0, 0, 0);
            __syncthreads();  // one barrier per K-step; drains next-buf loads
            cur ^= 1;
        }
    } else {
        // --- register staging with fp32->bf16 convert ---
        __shared__ short lA[128 * 32];
        __shared__ short lB[128 * 32];
        const int ar0 = t >> 2, ac0 = (t & 3) * 8;
        const int ar1 = ar0 + 64, ac1 = ac0;
        const int arow0 = min(m0 + ar0, M - 1);
        const int arow1 = min(m0 + ar1, M - 1);
        for (int k0 = 0; k0 < K; k0 += 32) {
            const short8 va0 = lda8<SRC>(Af, A2, (size_t)arow0 * K + k0 + ac0);
            const short8 va1 = lda8<SRC>(Af, A2, (size_t)arow1 * K + k0 + ac1);
            const short8 vb0 = *(const short8*)(BT + (size_t)(n0 + ar0) * ldb + k0 + ac0);
            const short8 vb1 = *(const short8*)(BT + (size_t)(n0 + ar1) * ldb + k0 + ac1);
            __syncthreads();
            *(short8*)&lA[ar0 * 32 + ac0] = va0;
            *(short8*)&lA[ar1 * 32 + ac1] = va1;
            *(short8*)&lB[ar0 * 32 + ac0] = vb0;
            *(short8*)&lB[ar1 * 32 + ac1] = vb1;
            __syncthreads();
            short8 af[4], bfr[4];
#pragma unroll
            for (int mi = 0; mi < 4; ++mi)
                af[mi] = *(const short8*)&lA[(wr * 64 + mi * 16 + l16) * 32 + quad * 8];
#pragma unroll
            for (int ni = 0; ni < 4; ++ni)
                bfr[ni] = *(const short8*)&lB[(wc * 64 + ni * 16 + l16) * 32 + quad * 8];
#pragma unroll
            for (int mi = 0; mi < 4; ++mi)
#pragma unroll
                for (int ni = 0; ni < 4; ++ni)
                    acc[mi][ni] = __builtin_amdgcn_mfma_f32_16x16x32_bf16(
                        af[mi], bfr[ni], acc[mi][ni], 0, 0, 0);
        }
    }

#pragma unroll
    for (int ni = 0; ni < 4; ++ni) {
        const int gc = n0 + wc * 64 + ni * 16 + l16;
        const float bia = bias[gc];
#pragma unroll
        for (int mi = 0; mi < 4; ++mi) {
#pragma unroll
            for (int r = 0; r < 4; ++r) {
                const int gr = m0 + wr * 64 + mi * 16 + quad * 4 + r;
                if (gr < M) {
                    float v = acc[mi][ni][r] + bia;
                    if (EPI == 3) {
                        v += ((const float*)resid)[(size_t)gr * ldc + gc];
                        ((float*)C)[(size_t)gr * ldc + gc] = v;
                    } else if (EPI == 4) {
                        v += bf2f(((const short*)resid)[(size_t)gr * ldc + gc]);
                        ((float*)C)[(size_t)gr * ldc + gc] = v;
                    } else if (EPI == 5) {
                        // head-major scatter: [B][NH][LQ][HD]
                        const int b = gr / LQn, s = gr - b * LQn;
                        const int hh = gc >> 5, d = gc & 31;
                        ((short*)C)[(((size_t)b * 8 + hh) * LQn + s) * 32 + d] = f2bf(v);
                    } else {
                        if (EPI == 2) v = fmaxf(v, 0.f);
                        ((short*)C)[(size_t)gr * ldc + gc] = f2bf(v);
                    }
                }
            }
        }
    }
}

// ---------------------------------------------------------------------------
// MS deformable sampling, head-major value [B][NH][LQ][HD].
// 4 threads per (row, head); each owns 8 of 32 dims. Branchless bilinear;
// softmax fused. __launch_bounds__(256,4): cap VGPR at 128 -> 4 waves/SIMD.
// ---------------------------------------------------------------------------
__global__ __launch_bounds__(256, 4) void sample_k(const short* __restrict__ value,
                                                   const short* __restrict__ offaw,
                                                   const float* __restrict__ refp,
                                                   short* __restrict__ attn) {
    const int t = blockIdx.x * 256 + threadIdx.x;
    const int grp = t >> 2, sub = t & 3;
    if (grp >= MREAL * 8) return;
    const int row = grp >> 3, h = grp & 7;
    const int b = row / LQn;
    const int L_[4] = {100, 50, 25, 13};
    const int O_[4] = {0, 10000, 12500, 13125};
    const short* op = offaw + (size_t)row * 384 + h * 32;
    const short* ap = offaw + (size_t)row * 384 + 256 + h * 16;

    // fused softmax over 16 logits (fp32 weights)
    float wgt[16];
    {
        const short8 a0 = *(const short8*)ap;
        const short8 a1 = *(const short8*)(ap + 8);
#pragma unroll
        for (int j = 0; j < 8; ++j) { wgt[j] = bf2f(a0[j]); wgt[j + 8] = bf2f(a1[j]); }
        float m = wgt[0];
#pragma unroll
        for (int j = 1; j < 16; ++j) m = fmaxf(m, wgt[j]);
        float s = 0.f;
#pragma unroll
        for (int j = 0; j < 16; ++j) { wgt[j] = __expf(wgt[j] - m); s += wgt[j]; }
        const float inv = 1.f / s;
#pragma unroll
        for (int j = 0; j < 16; ++j) wgt[j] *= inv;
    }

    const float4 r01 = ((const float4*)(refp + (size_t)row * 8))[0];
    const float4 r23 = ((const float4*)(refp + (size_t)row * 8))[1];
    const float rxs[4] = {r01.x, r01.z, r23.x, r23.z};
    const float rys[4] = {r01.y, r01.w, r23.y, r23.w};

    const short* vplane = value + ((size_t)(b * 8 + h) * LQn) * 32 + sub * 8;
    float acc[8];
#pragma unroll
    for (int j = 0; j < 8; ++j) acc[j] = 0.f;

#pragma unroll
    for (int l = 0; l < 4; ++l) {
        const int L = L_[l];
        const float Lf = (float)L;
        const short* vlev = vplane + (size_t)O_[l] * 32;
        const short8 ov = *(const short8*)(op + l * 8);
        const float rx = rxs[l], ry = rys[l];
#pragma unroll
        for (int p = 0; p < 4; ++p) {
            const float x = fmaf(rx, Lf, bf2f(ov[p * 2 + 0]) - 0.5f);
            const float y = fmaf(ry, Lf, bf2f(ov[p * 2 + 1]) - 0.5f);
            const float xf = floorf(x), yf = floorf(y);
            const int ix = (int)xf, iy = (int)yf;
            const float fx = x - xf, fy = y - yf;
            const float aw = wgt[l * 4 + p];
            const float vx0 = ((unsigned)ix < (unsigned)L) ? 1.f : 0.f;
            const float vx1 = ((unsigned)(ix + 1) < (unsigned)L) ? 1.f : 0.f;
            const float vy0 = ((unsigned)iy < (unsigned)L) ? 1.f : 0.f;
            const float vy1 = ((unsigned)(iy + 1) < (unsigned)L) ? 1.f : 0.f;
            const float gx0 = (1.f - fx) * aw, gx1 = fx * aw;
            const float w00 = gx0 * (1.f - fy) * vx0 * vy0;
            const float w10 = gx1 * (1.f - fy) * vx1 * vy0;
            const float w01 = gx0 * fy * vx0 * vy1;
            const float w11 = gx1 * fy * vx1 * vy1;
            const int ix0 = min(max(ix, 0), L - 1);
            const int ix1 = min(max(ix + 1, 0), L - 1);
            const int iy0 = min(max(iy, 0), L - 1);
            const int iy1 = min(max(iy + 1, 0), L - 1);
            // 4 independent loads -> all in flight together
            const short8 v00 = *(const short8*)(vlev + ((size_t)iy0 * L + ix0) * 32);
            const short8 v10 = *(const short8*)(vlev + ((size_t)iy0 * L + ix1) * 32);
            const short8 v01 = *(const short8*)(vlev + ((size_t)iy1 * L + ix0) * 32);
            const short8 v11 = *(const short8*)(vlev + ((size_t)iy1 * L + ix1) * 32);
#pragma unroll
            for (int j = 0; j < 8; ++j)
                acc[j] += w00 * bf2f(v00[j]) + w10 * bf2f(v10[j]) +
                          w01 * bf2f(v01[j]) + w11 * bf2f(v11[j]);
        }
    }
    short8 o;
#pragma unroll
    for (int j = 0; j < 8; ++j) o[j] = f2bf(acc[j]);
    *(short8*)(attn + (size_t)row * 256 + h * 32 + sub * 8) = o;
}

// ---------------------------------------------------------------------------
// Row LayerNorm over 256 cols. One wave per row, float4 per lane.
// OUT_BF=0: fp32 out (in-place safe). OUT_BF=1: bf16 out only.
// ---------------------------------------------------------------------------
template <int OUT_BF>
__global__ __launch_bounds__(256) void ln_rows(const float* in,
                                               const float* __restrict__ g,
                                               const float* __restrict__ be,
                                               float* outf, short* outb, int M) {
    const int row = blockIdx.x * 4 + (threadIdx.x >> 6);
    if (row >= M) return;
    const int lane = threadIdx.x & 63;
    const float4 v = ((const float4*)(in + (size_t)row * 256))[lane];
    float s = v.x + v.y + v.z + v.w;
#pragma unroll
    for (int o = 32; o > 0; o >>= 1) s += __shfl_xor(s, o);
    const float mean = s * (1.0f / 256.0f);
    const float dx = v.x - mean, dy = v.y - mean, dz = v.z - mean, dw = v.w - mean;
    float q = dx * dx + dy * dy + dz * dz + dw * dw;
#pragma unroll
    for (int o = 32; o > 0; o >>= 1) q += __shfl_xor(q, o);
    const float rstd = rsqrtf(q * (1.0f / 256.0f) + 1e-5f);
    const float4 gv = ((const float4*)g)[lane];
    const float4 bv = ((const float4*)be)[lane];
    float4 o4;
    o4.x = dx * rstd * gv.x + bv.x;
    o4.y = dy * rstd * gv.y + bv.y;
    o4.z = dz * rstd * gv.z + bv.z;
    o4.w = dw * rstd * gv.w + bv.w;
    if (OUT_BF) {
        short4v ob;
        ob.x = f2bf(o4.x); ob.y = f2bf(o4.y); ob.z = f2bf(o4.z); ob.w = f2bf(o4.w);
        ((short4v*)(outb + (size_t)row * 256))[lane] = ob;
    } else {
        ((float4*)(outf + (size_t)row * 256))[lane] = o4;
    }
}

// ---------------------------------------------------------------------------
extern "C" void kernel_launch(void* const* d_in, const int* in_sizes, int n_in,
                              void* d_out, int out_size, void* d_ws, size_t ws_size,
                              hipStream_t stream) {
    (void)in_sizes; (void)n_in; (void)out_size; (void)ws_size;
    const float* src  = (const float*)d_in[0];
    const float* pos  = (const float*)d_in[1];
    const float* refp = (const float*)d_in[2];
    const float* Wv = (const float*)d_in[5];
    const float* bv = (const float*)d_in[6];
    const float* Ws = (const float*)d_in[7];
    const float* bs = (const float*)d_in[8];
    const float* Wa = (const float*)d_in[9];
    const float* ba = (const float*)d_in[10];
    const float* Wo = (const float*)d_in[11];
    const float* bo = (const float*)d_in[12];
    const float* W1 = (const float*)d_in[13];
    const float* b1 = (const float*)d_in[14];
    const float* W2 = (const float*)d_in[15];
    const float* b2 = (const float*)d_in[16];
    const float* g1 = (const float*)d_in[17];
    const float* be1 = (const float*)d_in[18];
    const float* g2 = (const float*)d_in[19];
    const float* be2 = (const float*)d_in[20];

    char* ws = (char*)d_ws;
    size_t off = 0;
    auto take = [&](size_t bytes) {
        char* p = ws + off;
        off += (bytes + 255) & ~(size_t)255;
        return p;
    };
    short* WvT  = (short*)take(256 * 256 * 2);
    short* WsaT = (short*)take(384 * 256 * 2);
    short* WoT  = (short*)take(256 * 256 * 2);
    short* W1T  = (short*)take(1024 * 256 * 2);
    short* W2T  = (short*)take(256 * 1024 * 2);
    float* bsa  = (float*)take(384 * 4);
    float* zerob = (float*)take(256 * 4);
    short* value_h = (short*)take((size_t)MP * 256 * 2);  // head-major value; later x_bf
    short* offaw   = (short*)take((size_t)MP * 384 * 2);  // later h part 1
    short* attn_bf = (short*)take((size_t)MP * 256 * 2);  // later h part 2
    // total ~96.9 MB

    short* x_bf = value_h;         // after sampling, value dead
    short* h    = offaw;           // h half 54.5 MB spans offaw(40.9)+attn(27.3)
    float* z    = (float*)d_out;

    // Weight prep
    transpose_w<<<(256 * 256) / 256, 256, 0, stream>>>(Wv, WvT, 256, 256);
    transpose_w<<<(256 * 256) / 256, 256, 0, stream>>>(Ws, WsaT, 256, 256);
    transpose_w<<<(256 * 128) / 256, 256, 0, stream>>>(Wa, WsaT + 256 * 256, 256, 128);
    transpose_w<<<(256 * 256) / 256, 256, 0, stream>>>(Wo, WoT, 256, 256);
    transpose_w<<<(256 * 1024) / 256, 256, 0, stream>>>(W1, W1T, 256, 1024);
    transpose_w<<<(1024 * 256) / 256, 256, 0, stream>>>(W2, W2T, 1024, 256);
    prep_small_k<<<1, 384, 0, stream>>>(bs, ba, bsa, zerob);

    // G1: value (head-major) = bf16(src) @ WvT + bv
    gemm_bt<1, 5><<<dim3(MT, 2), 256, 0, stream>>>(
        nullptr, src, nullptr, WvT, bv, nullptr, value_h, MREAL, 256, 256, 256, 256);
    // G2: offaw = bf16(src+pos) @ WsaT + bsa  (logits; softmax fused in sample)
    gemm_bt<2, 1><<<dim3(MT, 3), 256, 0, stream>>>(
        nullptr, src, pos, WsaT, bsa, nullptr, offaw, MREAL, 256, 384, 256, 384);
    // Deformable sampling (softmax inside)
    sample_k<<<(MREAL * 32) / 256, 256, 0, stream>>>(value_h, offaw, refp, attn_bf);
    // G4: z = src + attn @ WoT + bo
    gemm_bt<0, 3><<<dim3(MT, 2), 256, 0, stream>>>(
        attn_bf, nullptr, nullptr, WoT, bo, src, z, MREAL, 256, 256, 256, 256);
    // LN1: x_bf = LN(z)   (bf16 only)
    ln_rows<1><<<(MREAL + 3) / 4, 256, 0, stream>>>(z, g1, be1, nullptr, x_bf, MREAL);
    // FFN in 2 half-passes over DFFN
    for (int p = 0; p < 2; ++p) {
        gemm_bt<0, 2><<<dim3(MT, 4), 256, 0, stream>>>(
            x_bf, nullptr, nullptr, W1T + (size_t)p * 512 * 256, b1 + p * 512,
            nullptr, h, MREAL, 256, 512, 256, 512);
        if (p == 0)
            gemm_bt<0, 4><<<dim3(MT, 2), 256, 0, stream>>>(
                h, nullptr, nullptr, W2T + 0, b2, x_bf, z,
                MREAL, 512, 256, 1024, 256);
        else
            gemm_bt<0, 3><<<dim3(MT, 2), 256, 0, stream>>>(
                h, nullptr, nullptr, W2T + 512, zerob, z, z,
                MREAL, 512, 256, 1024, 256);
    }
    // LN2 in place
    ln_rows<0><<<(MREAL + 3) / 4, 256, 0, stream>>>(z, g2, be2, z, nullptr, MREAL);
}

// Round 7
// 550.253 us; speedup vs baseline: 2.2461x; 2.2461x over previous
//
#include <hip/hip_runtime.h>

// ---------------------------------------------------------------------------
// DeformableTransformerEncoderLayer on MI355X (gfx950)
// B=4, LQ=13294, DM=256, DFFN=1024, NL=4, NH=8, NP=4, HD=32
// M = 53176 rows, padded tiles to Mp = 53248 = 416*128.
// Round 7:
//  - sample_k restructured: 16 threads per (row,head) = (level, dimgroup);
//    each thread does its level's 4 points, cross-level sum via 2 shfl_xor
//    steps. No launch_bounds cap (R6's (256,4) forced VGPR=64 -> 1.9GB of
//    scratch spill traffic). XCD-chunked block swizzle for L2 locality.
// Pipeline:
//   G1: value_h = bf16(src) @ WvT + bv        (head-major scatter epilogue)
//   G2: offaw   = bf16(src+pos) @ [Ws|Wa]T + [bs|ba]  (bf16 logits, N=384)
//   sample:     attn_bf = MSDeformAttn(value_h, offaw, refp)  (softmax inside)
//   G4: z(d_out) = src + attn_bf @ WoT + bo   (fp32 + resid)
//   LN1: x_bf <- LN(z)                        (bf16, overlays value_h)
//   2x { G5p: h = relu(x_bf @ W1T[p] + b1[p])     (h overlays offaw+attn)
//        G6p: z = resid + h @ W2T[:,p] (+b2 on p0; resid = x_bf on p0 else z) }
//   LN2: d_out = LN(z) in place
// Workspace ~97 MB.
// ---------------------------------------------------------------------------

#define LQn   13294
#define MREAL 53176
#define MP    53248
#define MT    416

typedef __attribute__((ext_vector_type(8))) short short8;
typedef __attribute__((ext_vector_type(4))) short short4v;
typedef __attribute__((ext_vector_type(4))) float f32x4;

__device__ __forceinline__ short f2bf(float f) {
    unsigned u = __float_as_uint(f);
    unsigned r = (u + 0x7FFFu + ((u >> 16) & 1u)) >> 16;  // RNE
    return (short)r;
}
__device__ __forceinline__ float bf2f(short b) {
    return __uint_as_float(((unsigned)(unsigned short)b) << 16);
}

#define GLOAD16(gp, lp)                                                        \
    __builtin_amdgcn_global_load_lds(                                          \
        (const __attribute__((address_space(1))) void*)(gp),                   \
        (__attribute__((address_space(3))) void*)(lp), 16, 0, 0)

// ---------------------------------------------------------------------------
__global__ __launch_bounds__(256) void transpose_w(const float* __restrict__ W,
                                                   short* __restrict__ WT,
                                                   int K, int N) {
    const int i = blockIdx.x * 256 + threadIdx.x;
    if (i >= K * N) return;
    const int n = i / K, k = i - n * K;
    WT[i] = f2bf(W[(size_t)k * N + n]);
}

__global__ void prep_small_k(const float* __restrict__ bs,
                             const float* __restrict__ ba,
                             float* __restrict__ bsa,
                             float* __restrict__ zerob) {
    const int t = threadIdx.x;
    if (t < 256) { bsa[t] = bs[t]; zerob[t] = 0.f; }
    else if (t < 384) bsa[t] = ba[t - 256];
}

// ---------------------------------------------------------------------------
// bf16 MFMA GEMM. 128x128 tile, BK=32, 4 waves, 16x16x32 MFMA.
// SRC: 0 = A bf16[M][K], dbuf global_load_lds staging (1 barrier/K-step);
//      1 = A fp32 (convert); 2 = A+A2 fp32 (q=src+pos)  (reg staging)
// EPI: 1 = bf16+bias; 2 = relu->bf16+bias; 3 = fp32+bias+fp32 resid;
//      4 = fp32+bias+bf16 resid; 5 = bf16+bias scattered head-major
// ---------------------------------------------------------------------------
template <int SRC>
__device__ __forceinline__ short8 lda8(const float* Af, const float* A2,
                                       size_t idx) {
    const float4 lo = *(const float4*)(Af + idx);
    const float4 hi = *(const float4*)(Af + idx + 4);
    float v[8] = {lo.x, lo.y, lo.z, lo.w, hi.x, hi.y, hi.z, hi.w};
    if constexpr (SRC == 2) {
        const float4 lo2 = *(const float4*)(A2 + idx);
        const float4 hi2 = *(const float4*)(A2 + idx + 4);
        v[0] += lo2.x; v[1] += lo2.y; v[2] += lo2.z; v[3] += lo2.w;
        v[4] += hi2.x; v[5] += hi2.y; v[6] += hi2.z; v[7] += hi2.w;
    }
    short8 r;
#pragma unroll
    for (int j = 0; j < 8; ++j) r[j] = f2bf(v[j]);
    return r;
}

template <int SRC, int EPI>
__global__ __launch_bounds__(256) void gemm_bt(const short* __restrict__ Ab,
                                               const float* __restrict__ Af,
                                               const float* __restrict__ A2,
                                               const short* __restrict__ BT,
                                               const float* __restrict__ bias,
                                               const void* resid,
                                               void* C,
                                               int M, int K, int N,
                                               int ldb, int ldc) {
    const int t = threadIdx.x;
    const int m0 = blockIdx.x * 128, n0 = blockIdx.y * 128;
    const int wid = t >> 6, lane = t & 63;
    const int wr = wid >> 1, wc = wid & 1;
    const int quad = lane >> 4, l16 = lane & 15;

    f32x4 acc[4][4];
#pragma unroll
    for (int i = 0; i < 4; ++i)
#pragma unroll
        for (int j = 0; j < 4; ++j) acc[i][j] = (f32x4){0.f, 0.f, 0.f, 0.f};

    if constexpr (SRC == 0) {
        // --- 2-phase double-buffered global_load_lds staging ---
        __shared__ short lA[2][128 * 32];
        __shared__ short lB[2][128 * 32];
        const int grow = wid * 32 + (lane >> 2);   // row this lane feeds
        const int gcol = (lane & 3) * 8;           // 16B within row
        auto stage = [&](int buf, int k0) {
            GLOAD16(Ab + (size_t)(m0 + grow) * K + k0 + gcol,
                    &lA[buf][(wid * 32) * 32]);
            GLOAD16(Ab + (size_t)(m0 + grow + 16) * K + k0 + gcol,
                    &lA[buf][(wid * 32 + 16) * 32]);
            GLOAD16(BT + (size_t)(n0 + grow) * ldb + k0 + gcol,
                    &lB[buf][(wid * 32) * 32]);
            GLOAD16(BT + (size_t)(n0 + grow + 16) * ldb + k0 + gcol,
                    &lB[buf][(wid * 32 + 16) * 32]);
        };
        stage(0, 0);
        __syncthreads();   // vmcnt(0) drained by compiler before barrier
        int cur = 0;
        for (int k0 = 0; k0 < K; k0 += 32) {
            if (k0 + 32 < K) stage(cur ^ 1, k0 + 32);  // in flight during MFMA
            short8 af[4], bfr[4];
#pragma unroll
            for (int mi = 0; mi < 4; ++mi)
                af[mi] = *(const short8*)&lA[cur][(wr * 64 + mi * 16 + l16) * 32 + quad * 8];
#pragma unroll
            for (int ni = 0; ni < 4; ++ni)
                bfr[ni] = *(const short8*)&lB[cur][(wc * 64 + ni * 16 + l16) * 32 + quad * 8];
#pragma unroll
            for (int mi = 0; mi < 4; ++mi)
#pragma unroll
                for (int ni = 0; ni < 4; ++ni)
                    acc[mi][ni] = __builtin_amdgcn_mfma_f32_16x16x32_bf16(
                        af[mi], bfr[ni], acc[mi][ni], 0, 0, 0);
            __syncthreads();  // one barrier per K-step; drains next-buf loads
            cur ^= 1;
        }
    } else {
        // --- register staging with fp32->bf16 convert ---
        __shared__ short lA[128 * 32];
        __shared__ short lB[128 * 32];
        const int ar0 = t >> 2, ac0 = (t & 3) * 8;
        const int ar1 = ar0 + 64, ac1 = ac0;
        const int arow0 = min(m0 + ar0, M - 1);
        const int arow1 = min(m0 + ar1, M - 1);
        for (int k0 = 0; k0 < K; k0 += 32) {
            const short8 va0 = lda8<SRC>(Af, A2, (size_t)arow0 * K + k0 + ac0);
            const short8 va1 = lda8<SRC>(Af, A2, (size_t)arow1 * K + k0 + ac1);
            const short8 vb0 = *(const short8*)(BT + (size_t)(n0 + ar0) * ldb + k0 + ac0);
            const short8 vb1 = *(const short8*)(BT + (size_t)(n0 + ar1) * ldb + k0 + ac1);
            __syncthreads();
            *(short8*)&lA[ar0 * 32 + ac0] = va0;
            *(short8*)&lA[ar1 * 32 + ac1] = va1;
            *(short8*)&lB[ar0 * 32 + ac0] = vb0;
            *(short8*)&lB[ar1 * 32 + ac1] = vb1;
            __syncthreads();
            short8 af[4], bfr[4];
#pragma unroll
            for (int mi = 0; mi < 4; ++mi)
                af[mi] = *(const short8*)&lA[(wr * 64 + mi * 16 + l16) * 32 + quad * 8];
#pragma unroll
            for (int ni = 0; ni < 4; ++ni)
                bfr[ni] = *(const short8*)&lB[(wc * 64 + ni * 16 + l16) * 32 + quad * 8];
#pragma unroll
            for (int mi = 0; mi < 4; ++mi)
#pragma unroll
                for (int ni = 0; ni < 4; ++ni)
                    acc[mi][ni] = __builtin_amdgcn_mfma_f32_16x16x32_bf16(
                        af[mi], bfr[ni], acc[mi][ni], 0, 0, 0);
        }
    }

#pragma unroll
    for (int ni = 0; ni < 4; ++ni) {
        const int gc = n0 + wc * 64 + ni * 16 + l16;
        const float bia = bias[gc];
#pragma unroll
        for (int mi = 0; mi < 4; ++mi) {
#pragma unroll
            for (int r = 0; r < 4; ++r) {
                const int gr = m0 + wr * 64 + mi * 16 + quad * 4 + r;
                if (gr < M) {
                    float v = acc[mi][ni][r] + bia;
                    if (EPI == 3) {
                        v += ((const float*)resid)[(size_t)gr * ldc + gc];
                        ((float*)C)[(size_t)gr * ldc + gc] = v;
                    } else if (EPI == 4) {
                        v += bf2f(((const short*)resid)[(size_t)gr * ldc + gc]);
                        ((float*)C)[(size_t)gr * ldc + gc] = v;
                    } else if (EPI == 5) {
                        // head-major scatter: [B][NH][LQ][HD]
                        const int b = gr / LQn, s = gr - b * LQn;
                        const int hh = gc >> 5, d = gc & 31;
                        ((short*)C)[(((size_t)b * 8 + hh) * LQn + s) * 32 + d] = f2bf(v);
                    } else {
                        if (EPI == 2) v = fmaxf(v, 0.f);
                        ((short*)C)[(size_t)gr * ldc + gc] = f2bf(v);
                    }
                }
            }
        }
    }
}

// ---------------------------------------------------------------------------
// MS deformable sampling, head-major value [B][NH][LQ][HD].
// 16 threads per (row, head): thread = (level l, dimgroup sub).
// Each thread: its level's 4 points x 4 corners (unroll 2), acc[8];
// softmax max/sum and final acc summed across the 4 level-lanes via
// shfl_xor masks {4,8}. Lanes with l==0 write the 32-dim result.
// Block = 256 threads = 16 groups; XCD-chunked bijective block swizzle.
// ---------------------------------------------------------------------------
__global__ __launch_bounds__(256) void sample_k(const short* __restrict__ value,
                                                const short* __restrict__ offaw,
                                                const float* __restrict__ refp,
                                                short* __restrict__ attn,
                                                int nwg) {
    // bijective XCD-chunk swizzle (m204): XCD k gets a contiguous block range
    int wg = blockIdx.x;
    {
        const int q = nwg >> 3, r = nwg & 7;
        const int xcd = wg & 7, idx = wg >> 3;
        wg = (xcd < r ? xcd * (q + 1) : r * (q + 1) + (xcd - r) * q) + idx;
    }
    const int tid = threadIdx.x;
    const int grp = wg * 16 + (tid >> 4);          // (row,head) id
    const int s16 = tid & 15;
    const int l = s16 >> 2, sub = s16 & 3;
    const int row = grp >> 3, h = grp & 7;
    const int b = row / LQn;
    const int L = (l == 0) ? 100 : (l == 1) ? 50 : (l == 2) ? 25 : 13;
    const int O = (l == 0) ? 0 : (l == 1) ? 10000 : (l == 2) ? 12500 : 13125;
    const float Lf = (float)L;

    const short* op = offaw + (size_t)row * 384 + h * 32;
    const short* ap = offaw + (size_t)row * 384 + 256 + h * 16;

    // --- softmax over 16 logits, distributed: 4 per thread + 2 shfl steps ---
    const short4v alog = *(const short4v*)(ap + l * 4);
    float lg[4];
#pragma unroll
    for (int j = 0; j < 4; ++j) lg[j] = bf2f(alog[j]);
    float m = fmaxf(fmaxf(lg[0], lg[1]), fmaxf(lg[2], lg[3]));
    m = fmaxf(m, __shfl_xor(m, 4));
    m = fmaxf(m, __shfl_xor(m, 8));
    float s = 0.f;
#pragma unroll
    for (int j = 0; j < 4; ++j) { lg[j] = __expf(lg[j] - m); s += lg[j]; }
    s += __shfl_xor(s, 4);
    s += __shfl_xor(s, 8);
    const float inv = 1.f / s;

    // --- positions for this level ---
    const float2 rxy = *(const float2*)(refp + (size_t)row * 8 + l * 2);
    const short8 ov = *(const short8*)(op + l * 8);
    const short* vlev = value + ((size_t)(b * 8 + h) * LQn + O) * 32 + sub * 8;

    float acc[8];
#pragma unroll
    for (int j = 0; j < 8; ++j) acc[j] = 0.f;

#pragma unroll 2
    for (int p = 0; p < 4; ++p) {
        const float x = fmaf(rxy.x, Lf, bf2f(ov[p * 2 + 0]) - 0.5f);
        const float y = fmaf(rxy.y, Lf, bf2f(ov[p * 2 + 1]) - 0.5f);
        const float xf = floorf(x), yf = floorf(y);
        const int ix = (int)xf, iy = (int)yf;
        const float fx = x - xf, fy = y - yf;
        const float aw = lg[p] * inv;
        const float vx0 = ((unsigned)ix < (unsigned)L) ? 1.f : 0.f;
        const float vx1 = ((unsigned)(ix + 1) < (unsigned)L) ? 1.f : 0.f;
        const float vy0 = ((unsigned)iy < (unsigned)L) ? 1.f : 0.f;
        const float vy1 = ((unsigned)(iy + 1) < (unsigned)L) ? 1.f : 0.f;
        const float gx0 = (1.f - fx) * aw, gx1 = fx * aw;
        const float w00 = gx0 * (1.f - fy) * vx0 * vy0;
        const float w10 = gx1 * (1.f - fy) * vx1 * vy0;
        const float w01 = gx0 * fy * vx0 * vy1;
        const float w11 = gx1 * fy * vx1 * vy1;
        const int ix0 = min(max(ix, 0), L - 1);
        const int ix1 = min(max(ix + 1, 0), L - 1);
        const int iy0 = min(max(iy, 0), L - 1);
        const int iy1 = min(max(iy + 1, 0), L - 1);
        const short8 v00 = *(const short8*)(vlev + ((size_t)iy0 * L + ix0) * 32);
        const short8 v10 = *(const short8*)(vlev + ((size_t)iy0 * L + ix1) * 32);
        const short8 v01 = *(const short8*)(vlev + ((size_t)iy1 * L + ix0) * 32);
        const short8 v11 = *(const short8*)(vlev + ((size_t)iy1 * L + ix1) * 32);
#pragma unroll
        for (int j = 0; j < 8; ++j)
            acc[j] += w00 * bf2f(v00[j]) + w10 * bf2f(v10[j]) +
                      w01 * bf2f(v01[j]) + w11 * bf2f(v11[j]);
    }

    // --- sum across the 4 level-lanes (xor bits 2,3 of lane id) ---
#pragma unroll
    for (int j = 0; j < 8; ++j) {
        acc[j] += __shfl_xor(acc[j], 4);
        acc[j] += __shfl_xor(acc[j], 8);
    }

    if (l == 0) {
        short8 o;
#pragma unroll
        for (int j = 0; j < 8; ++j) o[j] = f2bf(acc[j]);
        *(short8*)(attn + (size_t)row * 256 + h * 32 + sub * 8) = o;
    }
}

// ---------------------------------------------------------------------------
// Row LayerNorm over 256 cols. One wave per row, float4 per lane.
// OUT_BF=0: fp32 out (in-place safe). OUT_BF=1: bf16 out only.
// ---------------------------------------------------------------------------
template <int OUT_BF>
__global__ __launch_bounds__(256) void ln_rows(const float* in,
                                               const float* __restrict__ g,
                                               const float* __restrict__ be,
                                               float* outf, short* outb, int M) {
    const int row = blockIdx.x * 4 + (threadIdx.x >> 6);
    if (row >= M) return;
    const int lane = threadIdx.x & 63;
    const float4 v = ((const float4*)(in + (size_t)row * 256))[lane];
    float s = v.x + v.y + v.z + v.w;
#pragma unroll
    for (int o = 32; o > 0; o >>= 1) s += __shfl_xor(s, o);
    const float mean = s * (1.0f / 256.0f);
    const float dx = v.x - mean, dy = v.y - mean, dz = v.z - mean, dw = v.w - mean;
    float q = dx * dx + dy * dy + dz * dz + dw * dw;
#pragma unroll
    for (int o = 32; o > 0; o >>= 1) q += __shfl_xor(q, o);
    const float rstd = rsqrtf(q * (1.0f / 256.0f) + 1e-5f);
    const float4 gv = ((const float4*)g)[lane];
    const float4 bv = ((const float4*)be)[lane];
    float4 o4;
    o4.x = dx * rstd * gv.x + bv.x;
    o4.y = dy * rstd * gv.y + bv.y;
    o4.z = dz * rstd * gv.z + bv.z;
    o4.w = dw * rstd * gv.w + bv.w;
    if (OUT_BF) {
        short4v ob;
        ob.x = f2bf(o4.x); ob.y = f2bf(o4.y); ob.z = f2bf(o4.z); ob.w = f2bf(o4.w);
        ((short4v*)(outb + (size_t)row * 256))[lane] = ob;
    } else {
        ((float4*)(outf + (size_t)row * 256))[lane] = o4;
    }
}

// ---------------------------------------------------------------------------
extern "C" void kernel_launch(void* const* d_in, const int* in_sizes, int n_in,
                              void* d_out, int out_size, void* d_ws, size_t ws_size,
                              hipStream_t stream) {
    (void)in_sizes; (void)n_in; (void)out_size; (void)ws_size;
    const float* src  = (const float*)d_in[0];
    const float* pos  = (const float*)d_in[1];
    const float* refp = (const float*)d_in[2];
    const float* Wv = (const float*)d_in[5];
    const float* bv = (const float*)d_in[6];
    const float* Ws = (const float*)d_in[7];
    const float* bs = (const float*)d_in[8];
    const float* Wa = (const float*)d_in[9];
    const float* ba = (const float*)d_in[10];
    const float* Wo = (const float*)d_in[11];
    const float* bo = (const float*)d_in[12];
    const float* W1 = (const float*)d_in[13];
    const float* b1 = (const float*)d_in[14];
    const float* W2 = (const float*)d_in[15];
    const float* b2 = (const float*)d_in[16];
    const float* g1 = (const float*)d_in[17];
    const float* be1 = (const float*)d_in[18];
    const float* g2 = (const float*)d_in[19];
    const float* be2 = (const float*)d_in[20];

    char* ws = (char*)d_ws;
    size_t off = 0;
    auto take = [&](size_t bytes) {
        char* p = ws + off;
        off += (bytes + 255) & ~(size_t)255;
        return p;
    };
    short* WvT  = (short*)take(256 * 256 * 2);
    short* WsaT = (short*)take(384 * 256 * 2);
    short* WoT  = (short*)take(256 * 256 * 2);
    short* W1T  = (short*)take(1024 * 256 * 2);
    short* W2T  = (short*)take(256 * 1024 * 2);
    float* bsa  = (float*)take(384 * 4);
    float* zerob = (float*)take(256 * 4);
    short* value_h = (short*)take((size_t)MP * 256 * 2);  // head-major value; later x_bf
    short* offaw   = (short*)take((size_t)MP * 384 * 2);  // later h part 1
    short* attn_bf = (short*)take((size_t)MP * 256 * 2);  // later h part 2
    // total ~96.9 MB

    short* x_bf = value_h;         // after sampling, value dead
    short* h    = offaw;           // h half 54.5 MB spans offaw(40.9)+attn(27.3)
    float* z    = (float*)d_out;

    // Weight prep
    transpose_w<<<(256 * 256) / 256, 256, 0, stream>>>(Wv, WvT, 256, 256);
    transpose_w<<<(256 * 256) / 256, 256, 0, stream>>>(Ws, WsaT, 256, 256);
    transpose_w<<<(256 * 128) / 256, 256, 0, stream>>>(Wa, WsaT + 256 * 256, 256, 128);
    transpose_w<<<(256 * 256) / 256, 256, 0, stream>>>(Wo, WoT, 256, 256);
    transpose_w<<<(256 * 1024) / 256, 256, 0, stream>>>(W1, W1T, 256, 1024);
    transpose_w<<<(1024 * 256) / 256, 256, 0, stream>>>(W2, W2T, 1024, 256);
    prep_small_k<<<1, 384, 0, stream>>>(bs, ba, bsa, zerob);

    // G1: value (head-major) = bf16(src) @ WvT + bv
    gemm_bt<1, 5><<<dim3(MT, 2), 256, 0, stream>>>(
        nullptr, src, nullptr, WvT, bv, nullptr, value_h, MREAL, 256, 256, 256, 256);
    // G2: offaw = bf16(src+pos) @ WsaT + bsa  (logits; softmax fused in sample)
    gemm_bt<2, 1><<<dim3(MT, 3), 256, 0, stream>>>(
        nullptr, src, pos, WsaT, bsa, nullptr, offaw, MREAL, 256, 384, 256, 384);
    // Deformable sampling (16 threads per (row,head); softmax inside)
    {
        const int nwg = (MREAL * 8) / 16;  // 425408/16 = 26588 blocks
        sample_k<<<nwg, 256, 0, stream>>>(value_h, offaw, refp, attn_bf, nwg);
    }
    // G4: z = src + attn @ WoT + bo
    gemm_bt<0, 3><<<dim3(MT, 2), 256, 0, stream>>>(
        attn_bf, nullptr, nullptr, WoT, bo, src, z, MREAL, 256, 256, 256, 256);
    // LN1: x_bf = LN(z)   (bf16 only)
    ln_rows<1><<<(MREAL + 3) / 4, 256, 0, stream>>>(z, g1, be1, nullptr, x_bf, MREAL);
    // FFN in 2 half-passes over DFFN
    for (int p = 0; p < 2; ++p) {
        gemm_bt<0, 2><<<dim3(MT, 4), 256, 0, stream>>>(
            x_bf, nullptr, nullptr, W1T + (size_t)p * 512 * 256, b1 + p * 512,
            nullptr, h, MREAL, 256, 512, 256, 512);
        if (p == 0)
            gemm_bt<0, 4><<<dim3(MT, 2), 256, 0, stream>>>(
                h, nullptr, nullptr, W2T + 0, b2, x_bf, z,
                MREAL, 512, 256, 1024, 256);
        else
            gemm_bt<0, 3><<<dim3(MT, 2), 256, 0, stream>>>(
                h, nullptr, nullptr, W2T + 512, zerob, z, z,
                MREAL, 512, 256, 1024, 256);
    }
    // LN2 in place
    ln_rows<0><<<(MREAL + 3) / 4, 256, 0, stream>>>(z, g2, be2, z, nullptr, MREAL);
}

// Round 8
// 505.707 us; speedup vs baseline: 2.4440x; 1.0881x over previous
//
#include <hip/hip_runtime.h>

// ---------------------------------------------------------------------------
// DeformableTransformerEncoderLayer on MI355X (gfx950)
// B=4, LQ=13294, DM=256, DFFN=1024, NL=4, NH=8, NP=4, HD=32
// M = 53176 rows, padded tiles to Mp = 53248 = 416*128.
// Round 8:
//  - make_q: q_bf = bf16(src+pos) computed ONCE (was 3x fp32 inside G2);
//    q_bf overlays the attn region (dead until sample output). G2 -> dbuf
//    global_load_lds path.
//  - FFN split over M-halves (not N): h = half-rows x full 1024 cols in the
//    offaw+attn overlay; G6 K=1024 single pass; z written exactly once.
// Pipeline:
//   make_q: q_bf = bf16(src+pos)               (into attn region)
//   G1: value_h = bf16(src) @ WvT + bv         (head-major scatter epilogue)
//   G2: offaw = q_bf @ [Ws|Wa]T + [bs|ba]      (bf16 logits, N=384, dbuf)
//   sample: attn_bf = MSDeformAttn(value_h, offaw, refp)  (softmax inside)
//   G4: z(d_out) = src + attn_bf @ WoT + bo    (fp32 + resid)
//   LN1: x_bf <- LN(z)                         (bf16, overlays value_h)
//   2 halves: { G5: h = relu(x_bf[half] @ W1T + b1)   (h overlays offaw+attn)
//               G6: z[half] = x_bf[half] + h @ W2T + b2  (K=1024, one pass) }
//   LN2: d_out = LN(z) in place
// Workspace ~97 MB.
// ---------------------------------------------------------------------------

#define LQn   13294
#define MREAL 53176
#define MP    53248
#define MT    416
#define MHALF 26588
#define MTH   208

typedef __attribute__((ext_vector_type(8))) short short8;
typedef __attribute__((ext_vector_type(4))) short short4v;
typedef __attribute__((ext_vector_type(4))) float f32x4;

__device__ __forceinline__ short f2bf(float f) {
    unsigned u = __float_as_uint(f);
    unsigned r = (u + 0x7FFFu + ((u >> 16) & 1u)) >> 16;  // RNE
    return (short)r;
}
__device__ __forceinline__ float bf2f(short b) {
    return __uint_as_float(((unsigned)(unsigned short)b) << 16);
}

#define GLOAD16(gp, lp)                                                        \
    __builtin_amdgcn_global_load_lds(                                          \
        (const __attribute__((address_space(1))) void*)(gp),                   \
        (__attribute__((address_space(3))) void*)(lp), 16, 0, 0)

// ---------------------------------------------------------------------------
__global__ __launch_bounds__(256) void transpose_w(const float* __restrict__ W,
                                                   short* __restrict__ WT,
                                                   int K, int N) {
    const int i = blockIdx.x * 256 + threadIdx.x;
    if (i >= K * N) return;
    const int n = i / K, k = i - n * K;
    WT[i] = f2bf(W[(size_t)k * N + n]);
}

__global__ void prep_small_k(const float* __restrict__ bs,
                             const float* __restrict__ ba,
                             float* __restrict__ bsa) {
    const int t = threadIdx.x;
    if (t < 256) bsa[t] = bs[t];
    else if (t < 384) bsa[t] = ba[t - 256];
}

// q_bf[i] = bf16(src[i] + pos[i]), 8 elements per thread
__global__ __launch_bounds__(256) void make_q_k(const float* __restrict__ src,
                                                const float* __restrict__ pos,
                                                short* __restrict__ q_bf, int n8) {
    const int i = blockIdx.x * 256 + threadIdx.x;
    if (i >= n8) return;
    const float4 a0 = ((const float4*)src)[i * 2];
    const float4 a1 = ((const float4*)src)[i * 2 + 1];
    const float4 b0 = ((const float4*)pos)[i * 2];
    const float4 b1 = ((const float4*)pos)[i * 2 + 1];
    short8 o;
    o[0] = f2bf(a0.x + b0.x); o[1] = f2bf(a0.y + b0.y);
    o[2] = f2bf(a0.z + b0.z); o[3] = f2bf(a0.w + b0.w);
    o[4] = f2bf(a1.x + b1.x); o[5] = f2bf(a1.y + b1.y);
    o[6] = f2bf(a1.z + b1.z); o[7] = f2bf(a1.w + b1.w);
    ((short8*)q_bf)[i] = o;
}

// ---------------------------------------------------------------------------
// bf16 MFMA GEMM. 128x128 tile, BK=32, 4 waves, 16x16x32 MFMA.
// SRC: 0 = A bf16[*][K], dbuf global_load_lds staging (1 barrier/K-step);
//      1 = A fp32 (convert, reg staging)
// EPI: 1 = bf16+bias; 2 = relu->bf16+bias; 3 = fp32+bias+fp32 resid;
//      4 = fp32+bias+bf16 resid; 5 = bf16+bias scattered head-major
// ---------------------------------------------------------------------------
template <int SRC, int EPI>
__global__ __launch_bounds__(256) void gemm_bt(const short* __restrict__ Ab,
                                               const float* __restrict__ Af,
                                               const short* __restrict__ BT,
                                               const float* __restrict__ bias,
                                               const void* resid,
                                               void* C,
                                               int M, int K, int N,
                                               int ldb, int ldc) {
    const int t = threadIdx.x;
    const int m0 = blockIdx.x * 128, n0 = blockIdx.y * 128;
    const int wid = t >> 6, lane = t & 63;
    const int wr = wid >> 1, wc = wid & 1;
    const int quad = lane >> 4, l16 = lane & 15;

    f32x4 acc[4][4];
#pragma unroll
    for (int i = 0; i < 4; ++i)
#pragma unroll
        for (int j = 0; j < 4; ++j) acc[i][j] = (f32x4){0.f, 0.f, 0.f, 0.f};

    if constexpr (SRC == 0) {
        // --- 2-phase double-buffered global_load_lds staging ---
        __shared__ short lA[2][128 * 32];
        __shared__ short lB[2][128 * 32];
        const int grow = wid * 32 + (lane >> 2);   // row this lane feeds
        const int gcol = (lane & 3) * 8;           // 16B within row
        auto stage = [&](int buf, int k0) {
            GLOAD16(Ab + (size_t)(m0 + grow) * K + k0 + gcol,
                    &lA[buf][(wid * 32) * 32]);
            GLOAD16(Ab + (size_t)(m0 + grow + 16) * K + k0 + gcol,
                    &lA[buf][(wid * 32 + 16) * 32]);
            GLOAD16(BT + (size_t)(n0 + grow) * ldb + k0 + gcol,
                    &lB[buf][(wid * 32) * 32]);
            GLOAD16(BT + (size_t)(n0 + grow + 16) * ldb + k0 + gcol,
                    &lB[buf][(wid * 32 + 16) * 32]);
        };
        stage(0, 0);
        __syncthreads();   // vmcnt(0) drained by compiler before barrier
        int cur = 0;
        for (int k0 = 0; k0 < K; k0 += 32) {
            if (k0 + 32 < K) stage(cur ^ 1, k0 + 32);  // in flight during MFMA
            short8 af[4], bfr[4];
#pragma unroll
            for (int mi = 0; mi < 4; ++mi)
                af[mi] = *(const short8*)&lA[cur][(wr * 64 + mi * 16 + l16) * 32 + quad * 8];
#pragma unroll
            for (int ni = 0; ni < 4; ++ni)
                bfr[ni] = *(const short8*)&lB[cur][(wc * 64 + ni * 16 + l16) * 32 + quad * 8];
#pragma unroll
            for (int mi = 0; mi < 4; ++mi)
#pragma unroll
                for (int ni = 0; ni < 4; ++ni)
                    acc[mi][ni] = __builtin_amdgcn_mfma_f32_16x16x32_bf16(
                        af[mi], bfr[ni], acc[mi][ni], 0, 0, 0);
            __syncthreads();  // one barrier per K-step; drains next-buf loads
            cur ^= 1;
        }
    } else {
        // --- register staging with fp32->bf16 convert ---
        __shared__ short lA[128 * 32];
        __shared__ short lB[128 * 32];
        const int ar0 = t >> 2, ac0 = (t & 3) * 8;
        const int ar1 = ar0 + 64, ac1 = ac0;
        const int arow0 = min(m0 + ar0, M - 1);
        const int arow1 = min(m0 + ar1, M - 1);
        for (int k0 = 0; k0 < K; k0 += 32) {
            short8 va0, va1;
            {
                const size_t i0 = (size_t)arow0 * K + k0 + ac0;
                const size_t i1 = (size_t)arow1 * K + k0 + ac1;
                const float4 l0 = *(const float4*)(Af + i0);
                const float4 h0 = *(const float4*)(Af + i0 + 4);
                const float4 l1 = *(const float4*)(Af + i1);
                const float4 h1 = *(const float4*)(Af + i1 + 4);
                va0[0] = f2bf(l0.x); va0[1] = f2bf(l0.y); va0[2] = f2bf(l0.z);
                va0[3] = f2bf(l0.w); va0[4] = f2bf(h0.x); va0[5] = f2bf(h0.y);
                va0[6] = f2bf(h0.z); va0[7] = f2bf(h0.w);
                va1[0] = f2bf(l1.x); va1[1] = f2bf(l1.y); va1[2] = f2bf(l1.z);
                va1[3] = f2bf(l1.w); va1[4] = f2bf(h1.x); va1[5] = f2bf(h1.y);
                va1[6] = f2bf(h1.z); va1[7] = f2bf(h1.w);
            }
            const short8 vb0 = *(const short8*)(BT + (size_t)(n0 + ar0) * ldb + k0 + ac0);
            const short8 vb1 = *(const short8*)(BT + (size_t)(n0 + ar1) * ldb + k0 + ac1);
            __syncthreads();
            *(short8*)&lA[ar0 * 32 + ac0] = va0;
            *(short8*)&lA[ar1 * 32 + ac1] = va1;
            *(short8*)&lB[ar0 * 32 + ac0] = vb0;
            *(short8*)&lB[ar1 * 32 + ac1] = vb1;
            __syncthreads();
            short8 af[4], bfr[4];
#pragma unroll
            for (int mi = 0; mi < 4; ++mi)
                af[mi] = *(const short8*)&lA[(wr * 64 + mi * 16 + l16) * 32 + quad * 8];
#pragma unroll
            for (int ni = 0; ni < 4; ++ni)
                bfr[ni] = *(const short8*)&lB[(wc * 64 + ni * 16 + l16) * 32 + quad * 8];
#pragma unroll
            for (int mi = 0; mi < 4; ++mi)
#pragma unroll
                for (int ni = 0; ni < 4; ++ni)
                    acc[mi][ni] = __builtin_amdgcn_mfma_f32_16x16x32_bf16(
                        af[mi], bfr[ni], acc[mi][ni], 0, 0, 0);
        }
    }

#pragma unroll
    for (int ni = 0; ni < 4; ++ni) {
        const int gc = n0 + wc * 64 + ni * 16 + l16;
        const float bia = bias[gc];
#pragma unroll
        for (int mi = 0; mi < 4; ++mi) {
#pragma unroll
            for (int r = 0; r < 4; ++r) {
                const int gr = m0 + wr * 64 + mi * 16 + quad * 4 + r;
                if (gr < M) {
                    float v = acc[mi][ni][r] + bia;
                    if (EPI == 3) {
                        v += ((const float*)resid)[(size_t)gr * ldc + gc];
                        ((float*)C)[(size_t)gr * ldc + gc] = v;
                    } else if (EPI == 4) {
                        v += bf2f(((const short*)resid)[(size_t)gr * ldc + gc]);
                        ((float*)C)[(size_t)gr * ldc + gc] = v;
                    } else if (EPI == 5) {
                        // head-major scatter: [B][NH][LQ][HD]
                        const int b = gr / LQn, s = gr - b * LQn;
                        const int hh = gc >> 5, d = gc & 31;
                        ((short*)C)[(((size_t)b * 8 + hh) * LQn + s) * 32 + d] = f2bf(v);
                    } else {
                        if (EPI == 2) v = fmaxf(v, 0.f);
                        ((short*)C)[(size_t)gr * ldc + gc] = f2bf(v);
                    }
                }
            }
        }
    }
}

// ---------------------------------------------------------------------------
// MS deformable sampling, head-major value [B][NH][LQ][HD].
// 16 threads per (row, head): thread = (level l, dimgroup sub).
// Cross-level sums via shfl_xor {4,8}. XCD-chunked bijective block swizzle.
// ---------------------------------------------------------------------------
__global__ __launch_bounds__(256) void sample_k(const short* __restrict__ value,
                                                const short* __restrict__ offaw,
                                                const float* __restrict__ refp,
                                                short* __restrict__ attn,
                                                int nwg) {
    int wg = blockIdx.x;
    {
        const int q = nwg >> 3, r = nwg & 7;
        const int xcd = wg & 7, idx = wg >> 3;
        wg = (xcd < r ? xcd * (q + 1) : r * (q + 1) + (xcd - r) * q) + idx;
    }
    const int tid = threadIdx.x;
    const int grp = wg * 16 + (tid >> 4);          // (row,head) id
    const int s16 = tid & 15;
    const int l = s16 >> 2, sub = s16 & 3;
    const int row = grp >> 3, h = grp & 7;
    const int b = row / LQn;
    const int L = (l == 0) ? 100 : (l == 1) ? 50 : (l == 2) ? 25 : 13;
    const int O = (l == 0) ? 0 : (l == 1) ? 10000 : (l == 2) ? 12500 : 13125;
    const float Lf = (float)L;

    const short* op = offaw + (size_t)row * 384 + h * 32;
    const short* ap = offaw + (size_t)row * 384 + 256 + h * 16;

    // softmax over 16 logits, distributed: 4 per thread + 2 shfl steps
    const short4v alog = *(const short4v*)(ap + l * 4);
    float lg[4];
#pragma unroll
    for (int j = 0; j < 4; ++j) lg[j] = bf2f(alog[j]);
    float m = fmaxf(fmaxf(lg[0], lg[1]), fmaxf(lg[2], lg[3]));
    m = fmaxf(m, __shfl_xor(m, 4));
    m = fmaxf(m, __shfl_xor(m, 8));
    float s = 0.f;
#pragma unroll
    for (int j = 0; j < 4; ++j) { lg[j] = __expf(lg[j] - m); s += lg[j]; }
    s += __shfl_xor(s, 4);
    s += __shfl_xor(s, 8);
    const float inv = 1.f / s;

    const float2 rxy = *(const float2*)(refp + (size_t)row * 8 + l * 2);
    const short8 ov = *(const short8*)(op + l * 8);
    const short* vlev = value + ((size_t)(b * 8 + h) * LQn + O) * 32 + sub * 8;

    float acc[8];
#pragma unroll
    for (int j = 0; j < 8; ++j) acc[j] = 0.f;

#pragma unroll 2
    for (int p = 0; p < 4; ++p) {
        const float x = fmaf(rxy.x, Lf, bf2f(ov[p * 2 + 0]) - 0.5f);
        const float y = fmaf(rxy.y, Lf, bf2f(ov[p * 2 + 1]) - 0.5f);
        const float xf = floorf(x), yf = floorf(y);
        const int ix = (int)xf, iy = (int)yf;
        const float fx = x - xf, fy = y - yf;
        const float aw = lg[p] * inv;
        const float vx0 = ((unsigned)ix < (unsigned)L) ? 1.f : 0.f;
        const float vx1 = ((unsigned)(ix + 1) < (unsigned)L) ? 1.f : 0.f;
        const float vy0 = ((unsigned)iy < (unsigned)L) ? 1.f : 0.f;
        const float vy1 = ((unsigned)(iy + 1) < (unsigned)L) ? 1.f : 0.f;
        const float gx0 = (1.f - fx) * aw, gx1 = fx * aw;
        const float w00 = gx0 * (1.f - fy) * vx0 * vy0;
        const float w10 = gx1 * (1.f - fy) * vx1 * vy0;
        const float w01 = gx0 * fy * vx0 * vy1;
        const float w11 = gx1 * fy * vx1 * vy1;
        const int ix0 = min(max(ix, 0), L - 1);
        const int ix1 = min(max(ix + 1, 0), L - 1);
        const int iy0 = min(max(iy, 0), L - 1);
        const int iy1 = min(max(iy + 1, 0), L - 1);
        const short8 v00 = *(const short8*)(vlev + ((size_t)iy0 * L + ix0) * 32);
        const short8 v10 = *(const short8*)(vlev + ((size_t)iy0 * L + ix1) * 32);
        const short8 v01 = *(const short8*)(vlev + ((size_t)iy1 * L + ix0) * 32);
        const short8 v11 = *(const short8*)(vlev + ((size_t)iy1 * L + ix1) * 32);
#pragma unroll
        for (int j = 0; j < 8; ++j)
            acc[j] += w00 * bf2f(v00[j]) + w10 * bf2f(v10[j]) +
                      w01 * bf2f(v01[j]) + w11 * bf2f(v11[j]);
    }

#pragma unroll
    for (int j = 0; j < 8; ++j) {
        acc[j] += __shfl_xor(acc[j], 4);
        acc[j] += __shfl_xor(acc[j], 8);
    }

    if (l == 0) {
        short8 o;
#pragma unroll
        for (int j = 0; j < 8; ++j) o[j] = f2bf(acc[j]);
        *(short8*)(attn + (size_t)row * 256 + h * 32 + sub * 8) = o;
    }
}

// ---------------------------------------------------------------------------
// Row LayerNorm over 256 cols. One wave per row, float4 per lane.
// OUT_BF=0: fp32 out (in-place safe). OUT_BF=1: bf16 out only.
// ---------------------------------------------------------------------------
template <int OUT_BF>
__global__ __launch_bounds__(256) void ln_rows(const float* in,
                                               const float* __restrict__ g,
                                               const float* __restrict__ be,
                                               float* outf, short* outb, int M) {
    const int row = blockIdx.x * 4 + (threadIdx.x >> 6);
    if (row >= M) return;
    const int lane = threadIdx.x & 63;
    const float4 v = ((const float4*)(in + (size_t)row * 256))[lane];
    float s = v.x + v.y + v.z + v.w;
#pragma unroll
    for (int o = 32; o > 0; o >>= 1) s += __shfl_xor(s, o);
    const float mean = s * (1.0f / 256.0f);
    const float dx = v.x - mean, dy = v.y - mean, dz = v.z - mean, dw = v.w - mean;
    float q = dx * dx + dy * dy + dz * dz + dw * dw;
#pragma unroll
    for (int o = 32; o > 0; o >>= 1) q += __shfl_xor(q, o);
    const float rstd = rsqrtf(q * (1.0f / 256.0f) + 1e-5f);
    const float4 gv = ((const float4*)g)[lane];
    const float4 bv = ((const float4*)be)[lane];
    float4 o4;
    o4.x = dx * rstd * gv.x + bv.x;
    o4.y = dy * rstd * gv.y + bv.y;
    o4.z = dz * rstd * gv.z + bv.z;
    o4.w = dw * rstd * gv.w + bv.w;
    if (OUT_BF) {
        short4v ob;
        ob.x = f2bf(o4.x); ob.y = f2bf(o4.y); ob.z = f2bf(o4.z); ob.w = f2bf(o4.w);
        ((short4v*)(outb + (size_t)row * 256))[lane] = ob;
    } else {
        ((float4*)(outf + (size_t)row * 256))[lane] = o4;
    }
}

// ---------------------------------------------------------------------------
extern "C" void kernel_launch(void* const* d_in, const int* in_sizes, int n_in,
                              void* d_out, int out_size, void* d_ws, size_t ws_size,
                              hipStream_t stream) {
    (void)in_sizes; (void)n_in; (void)out_size; (void)ws_size;
    const float* src  = (const float*)d_in[0];
    const float* pos  = (const float*)d_in[1];
    const float* refp = (const float*)d_in[2];
    const float* Wv = (const float*)d_in[5];
    const float* bv = (const float*)d_in[6];
    const float* Ws = (const float*)d_in[7];
    const float* bs = (const float*)d_in[8];
    const float* Wa = (const float*)d_in[9];
    const float* ba = (const float*)d_in[10];
    const float* Wo = (const float*)d_in[11];
    const float* bo = (const float*)d_in[12];
    const float* W1 = (const float*)d_in[13];
    const float* b1 = (const float*)d_in[14];
    const float* W2 = (const float*)d_in[15];
    const float* b2 = (const float*)d_in[16];
    const float* g1 = (const float*)d_in[17];
    const float* be1 = (const float*)d_in[18];
    const float* g2 = (const float*)d_in[19];
    const float* be2 = (const float*)d_in[20];

    char* ws = (char*)d_ws;
    size_t off = 0;
    auto take = [&](size_t bytes) {
        char* p = ws + off;
        off += (bytes + 255) & ~(size_t)255;
        return p;
    };
    short* WvT  = (short*)take(256 * 256 * 2);
    short* WsaT = (short*)take(384 * 256 * 2);
    short* WoT  = (short*)take(256 * 256 * 2);
    short* W1T  = (short*)take(1024 * 256 * 2);
    short* W2T  = (short*)take(256 * 1024 * 2);
    float* bsa  = (float*)take(384 * 4);
    short* value_h = (short*)take((size_t)MP * 256 * 2);  // later x_bf
    short* offaw   = (short*)take((size_t)MP * 384 * 2);  // later h part 1
    short* attn_bf = (short*)take((size_t)MP * 256 * 2);  // q_bf, then attn, then h part 2
    // total ~96.9 MB

    short* q_bf = attn_bf;         // q dead before sample writes attn
    short* x_bf = value_h;         // after sampling, value dead
    short* h    = offaw;           // 26624 rows x 1024 cols bf16 = 54.5 MB
                                   // spans offaw(40.9)+attn(27.3) = 68.2 MB
    float* z    = (float*)d_out;

    // Weight prep
    transpose_w<<<(256 * 256) / 256, 256, 0, stream>>>(Wv, WvT, 256, 256);
    transpose_w<<<(256 * 256) / 256, 256, 0, stream>>>(Ws, WsaT, 256, 256);
    transpose_w<<<(256 * 128) / 256, 256, 0, stream>>>(Wa, WsaT + 256 * 256, 256, 128);
    transpose_w<<<(256 * 256) / 256, 256, 0, stream>>>(Wo, WoT, 256, 256);
    transpose_w<<<(256 * 1024) / 256, 256, 0, stream>>>(W1, W1T, 256, 1024);
    transpose_w<<<(1024 * 256) / 256, 256, 0, stream>>>(W2, W2T, 1024, 256);
    prep_small_k<<<1, 384, 0, stream>>>(bs, ba, bsa);

    // q_bf = bf16(src + pos)
    make_q_k<<<(MREAL * 32 + 255) / 256, 256, 0, stream>>>(src, pos, q_bf,
                                                           MREAL * 32);
    // G1: value (head-major) = bf16(src) @ WvT + bv
    gemm_bt<1, 5><<<dim3(MT, 2), 256, 0, stream>>>(
        nullptr, src, WvT, bv, nullptr, value_h, MREAL, 256, 256, 256, 256);
    // G2: offaw = q_bf @ WsaT + bsa  (dbuf gload path)
    gemm_bt<0, 1><<<dim3(MT, 3), 256, 0, stream>>>(
        q_bf, nullptr, WsaT, bsa, nullptr, offaw, MREAL, 256, 384, 256, 384);
    // Deformable sampling (softmax inside); writes attn over dead q_bf
    {
        const int nwg = (MREAL * 8) / 16;  // 26588 blocks
        sample_k<<<nwg, 256, 0, stream>>>(value_h, offaw, refp, attn_bf, nwg);
    }
    // G4: z = src + attn @ WoT + bo
    gemm_bt<0, 3><<<dim3(MT, 2), 256, 0, stream>>>(
        attn_bf, nullptr, WoT, bo, src, z, MREAL, 256, 256, 256, 256);
    // LN1: x_bf = LN(z)   (bf16 only)
    ln_rows<1><<<(MREAL + 3) / 4, 256, 0, stream>>>(z, g1, be1, nullptr, x_bf, MREAL);
    // FFN over two M-halves; h = full 1024 cols for half the rows
    for (int half = 0; half < 2; ++half) {
        const size_t ro = (size_t)half * MHALF;
        gemm_bt<0, 2><<<dim3(MTH, 8), 256, 0, stream>>>(
            x_bf + ro * 256, nullptr, W1T, b1, nullptr,
            h, MHALF, 256, 1024, 256, 1024);
        gemm_bt<0, 4><<<dim3(MTH, 2), 256, 0, stream>>>(
            h, nullptr, W2T, b2, x_bf + ro * 256,
            z + ro * 256, MHALF, 1024, 256, 1024, 256);
    }
    // LN2 in place
    ln_rows<0><<<(MREAL + 3) / 4, 256, 0, stream>>>(z, g2, be2, z, nullptr, MREAL);
}

// Round 9
// 457.538 us; speedup vs baseline: 2.7013x; 1.1053x over previous
//
#include <hip/hip_runtime.h>

// ---------------------------------------------------------------------------
// DeformableTransformerEncoderLayer on MI355X (gfx950)
// B=4, LQ=13294, DM=256, DFFN=1024, NL=4, NH=8, NP=4, HD=32
// M = 53176 rows, padded tiles to Mp = 53248 = 416*128.
// Round 9:
//  - prep_all: all weight transposes + bias concat in ONE dispatch.
//  - gemm_ln: 512-thread 128x256-tile GEMM with fused row-LayerNorm epilogue
//    (cross-wave LDS reduction). G4+LN1 fused (y never materialized);
//    G6+LN2 fused (final LN written once into d_out).
// Pipeline (9 dispatches):
//   prep_all; make_q;
//   G1: value_h = bf16(src) @ WvT + bv         (head-major scatter)
//   G2: offaw = q_bf @ [Ws|Wa]T + [bs|ba]      (bf16 logits, dbuf gload)
//   sample: attn_bf = MSDeformAttn(value_h, offaw, refp)
//   G4LN: x_bf = LN(src + attn_bf @ WoT + bo)  (gemm_ln<0>)
//   2 halves: { G5: h = relu(x_bf[half] @ W1T + b1)
//               G6LN: d_out[half] = LN(x_bf[half] + h @ W2T + b2) }
// Workspace ~97 MB.
// ---------------------------------------------------------------------------

#define LQn   13294
#define MREAL 53176
#define MP    53248
#define MT    416
#define MHALF 26588
#define MTH   208

typedef __attribute__((ext_vector_type(8))) short short8;
typedef __attribute__((ext_vector_type(4))) short short4v;
typedef __attribute__((ext_vector_type(4))) float f32x4;

__device__ __forceinline__ short f2bf(float f) {
    unsigned u = __float_as_uint(f);
    unsigned r = (u + 0x7FFFu + ((u >> 16) & 1u)) >> 16;  // RNE
    return (short)r;
}
__device__ __forceinline__ float bf2f(short b) {
    return __uint_as_float(((unsigned)(unsigned short)b) << 16);
}

#define GLOAD16(gp, lp)                                                        \
    __builtin_amdgcn_global_load_lds(                                          \
        (const __attribute__((address_space(1))) void*)(gp),                   \
        (__attribute__((address_space(3))) void*)(lp), 16, 0, 0)

// ---------------------------------------------------------------------------
// All weight prep in one dispatch: 6 transposes (fp32->bf16) + bias concat.
// 2944 transpose blocks + 1 bias block.
// ---------------------------------------------------------------------------
__global__ __launch_bounds__(256) void prep_all(
    const float* __restrict__ Wv, const float* __restrict__ Ws,
    const float* __restrict__ Wa, const float* __restrict__ Wo,
    const float* __restrict__ W1, const float* __restrict__ W2,
    const float* __restrict__ bs, const float* __restrict__ ba,
    short* __restrict__ WvT, short* __restrict__ WsaT,
    short* __restrict__ WoT, short* __restrict__ W1T,
    short* __restrict__ W2T, float* __restrict__ bsa) {
    const int bid = blockIdx.x, tid = threadIdx.x;
    const float* W; short* WT; int K, N, base;
    if (bid < 256)       { W = Wv; WT = WvT;             K = 256;  N = 256;  base = 0; }
    else if (bid < 512)  { W = Ws; WT = WsaT;            K = 256;  N = 256;  base = 256; }
    else if (bid < 640)  { W = Wa; WT = WsaT + 256 * 256; K = 256; N = 128;  base = 512; }
    else if (bid < 896)  { W = Wo; WT = WoT;             K = 256;  N = 256;  base = 640; }
    else if (bid < 1920) { W = W1; WT = W1T;             K = 256;  N = 1024; base = 896; }
    else if (bid < 2944) { W = W2; WT = W2T;             K = 1024; N = 256;  base = 1920; }
    else {
        if (tid < 256) bsa[tid] = bs[tid];
        else if (tid < 384) bsa[tid] = ba[tid - 256];
        return;
    }
    const int i = (bid - base) * 256 + tid;
    const int n = i / K, k = i - n * K;
    WT[i] = f2bf(W[(size_t)k * N + n]);
}

// q_bf[i] = bf16(src[i] + pos[i]), 8 elements per thread
__global__ __launch_bounds__(256) void make_q_k(const float* __restrict__ src,
                                                const float* __restrict__ pos,
                                                short* __restrict__ q_bf, int n8) {
    const int i = blockIdx.x * 256 + threadIdx.x;
    if (i >= n8) return;
    const float4 a0 = ((const float4*)src)[i * 2];
    const float4 a1 = ((const float4*)src)[i * 2 + 1];
    const float4 b0 = ((const float4*)pos)[i * 2];
    const float4 b1 = ((const float4*)pos)[i * 2 + 1];
    short8 o;
    o[0] = f2bf(a0.x + b0.x); o[1] = f2bf(a0.y + b0.y);
    o[2] = f2bf(a0.z + b0.z); o[3] = f2bf(a0.w + b0.w);
    o[4] = f2bf(a1.x + b1.x); o[5] = f2bf(a1.y + b1.y);
    o[6] = f2bf(a1.z + b1.z); o[7] = f2bf(a1.w + b1.w);
    ((short8*)q_bf)[i] = o;
}

// ---------------------------------------------------------------------------
// bf16 MFMA GEMM. 128x128 tile, BK=32, 4 waves, 16x16x32 MFMA.
// SRC: 0 = A bf16, dbuf global_load_lds; 1 = A fp32 (convert, reg staging)
// EPI: 1 = bf16+bias; 2 = relu->bf16+bias; 5 = bf16+bias scattered head-major
// ---------------------------------------------------------------------------
template <int SRC, int EPI>
__global__ __launch_bounds__(256) void gemm_bt(const short* __restrict__ Ab,
                                               const float* __restrict__ Af,
                                               const short* __restrict__ BT,
                                               const float* __restrict__ bias,
                                               void* C,
                                               int M, int K, int N,
                                               int ldb, int ldc) {
    const int t = threadIdx.x;
    const int m0 = blockIdx.x * 128, n0 = blockIdx.y * 128;
    const int wid = t >> 6, lane = t & 63;
    const int wr = wid >> 1, wc = wid & 1;
    const int quad = lane >> 4, l16 = lane & 15;

    f32x4 acc[4][4];
#pragma unroll
    for (int i = 0; i < 4; ++i)
#pragma unroll
        for (int j = 0; j < 4; ++j) acc[i][j] = (f32x4){0.f, 0.f, 0.f, 0.f};

    if constexpr (SRC == 0) {
        __shared__ short lA[2][128 * 32];
        __shared__ short lB[2][128 * 32];
        const int grow = wid * 32 + (lane >> 2);
        const int gcol = (lane & 3) * 8;
        auto stage = [&](int buf, int k0) {
            GLOAD16(Ab + (size_t)(m0 + grow) * K + k0 + gcol,
                    &lA[buf][(wid * 32) * 32]);
            GLOAD16(Ab + (size_t)(m0 + grow + 16) * K + k0 + gcol,
                    &lA[buf][(wid * 32 + 16) * 32]);
            GLOAD16(BT + (size_t)(n0 + grow) * ldb + k0 + gcol,
                    &lB[buf][(wid * 32) * 32]);
            GLOAD16(BT + (size_t)(n0 + grow + 16) * ldb + k0 + gcol,
                    &lB[buf][(wid * 32 + 16) * 32]);
        };
        stage(0, 0);
        __syncthreads();
        int cur = 0;
        for (int k0 = 0; k0 < K; k0 += 32) {
            if (k0 + 32 < K) stage(cur ^ 1, k0 + 32);
            short8 af[4], bfr[4];
#pragma unroll
            for (int mi = 0; mi < 4; ++mi)
                af[mi] = *(const short8*)&lA[cur][(wr * 64 + mi * 16 + l16) * 32 + quad * 8];
#pragma unroll
            for (int ni = 0; ni < 4; ++ni)
                bfr[ni] = *(const short8*)&lB[cur][(wc * 64 + ni * 16 + l16) * 32 + quad * 8];
#pragma unroll
            for (int mi = 0; mi < 4; ++mi)
#pragma unroll
                for (int ni = 0; ni < 4; ++ni)
                    acc[mi][ni] = __builtin_amdgcn_mfma_f32_16x16x32_bf16(
                        af[mi], bfr[ni], acc[mi][ni], 0, 0, 0);
            __syncthreads();
            cur ^= 1;
        }
    } else {
        __shared__ short lA[128 * 32];
        __shared__ short lB[128 * 32];
        const int ar0 = t >> 2, ac0 = (t & 3) * 8;
        const int ar1 = ar0 + 64, ac1 = ac0;
        const int arow0 = min(m0 + ar0, M - 1);
        const int arow1 = min(m0 + ar1, M - 1);
        for (int k0 = 0; k0 < K; k0 += 32) {
            short8 va0, va1;
            {
                const size_t i0 = (size_t)arow0 * K + k0 + ac0;
                const size_t i1 = (size_t)arow1 * K + k0 + ac1;
                const float4 l0 = *(const float4*)(Af + i0);
                const float4 h0 = *(const float4*)(Af + i0 + 4);
                const float4 l1 = *(const float4*)(Af + i1);
                const float4 h1 = *(const float4*)(Af + i1 + 4);
                va0[0] = f2bf(l0.x); va0[1] = f2bf(l0.y); va0[2] = f2bf(l0.z);
                va0[3] = f2bf(l0.w); va0[4] = f2bf(h0.x); va0[5] = f2bf(h0.y);
                va0[6] = f2bf(h0.z); va0[7] = f2bf(h0.w);
                va1[0] = f2bf(l1.x); va1[1] = f2bf(l1.y); va1[2] = f2bf(l1.z);
                va1[3] = f2bf(l1.w); va1[4] = f2bf(h1.x); va1[5] = f2bf(h1.y);
                va1[6] = f2bf(h1.z); va1[7] = f2bf(h1.w);
            }
            const short8 vb0 = *(const short8*)(BT + (size_t)(n0 + ar0) * ldb + k0 + ac0);
            const short8 vb1 = *(const short8*)(BT + (size_t)(n0 + ar1) * ldb + k0 + ac1);
            __syncthreads();
            *(short8*)&lA[ar0 * 32 + ac0] = va0;
            *(short8*)&lA[ar1 * 32 + ac1] = va1;
            *(short8*)&lB[ar0 * 32 + ac0] = vb0;
            *(short8*)&lB[ar1 * 32 + ac1] = vb1;
            __syncthreads();
            short8 af[4], bfr[4];
#pragma unroll
            for (int mi = 0; mi < 4; ++mi)
                af[mi] = *(const short8*)&lA[(wr * 64 + mi * 16 + l16) * 32 + quad * 8];
#pragma unroll
            for (int ni = 0; ni < 4; ++ni)
                bfr[ni] = *(const short8*)&lB[(wc * 64 + ni * 16 + l16) * 32 + quad * 8];
#pragma unroll
            for (int mi = 0; mi < 4; ++mi)
#pragma unroll
                for (int ni = 0; ni < 4; ++ni)
                    acc[mi][ni] = __builtin_amdgcn_mfma_f32_16x16x32_bf16(
                        af[mi], bfr[ni], acc[mi][ni], 0, 0, 0);
        }
    }

#pragma unroll
    for (int ni = 0; ni < 4; ++ni) {
        const int gc = n0 + wc * 64 + ni * 16 + l16;
        const float bia = bias[gc];
#pragma unroll
        for (int mi = 0; mi < 4; ++mi) {
#pragma unroll
            for (int r = 0; r < 4; ++r) {
                const int gr = m0 + wr * 64 + mi * 16 + quad * 4 + r;
                if (gr < M) {
                    float v = acc[mi][ni][r] + bia;
                    if (EPI == 5) {
                        const int b = gr / LQn, s = gr - b * LQn;
                        const int hh = gc >> 5, d = gc & 31;
                        ((short*)C)[(((size_t)b * 8 + hh) * LQn + s) * 32 + d] = f2bf(v);
                    } else {
                        if (EPI == 2) v = fmaxf(v, 0.f);
                        ((short*)C)[(size_t)gr * ldc + gc] = f2bf(v);
                    }
                }
            }
        }
    }
}

// ---------------------------------------------------------------------------
// 512-thread 128x256-tile GEMM with fused row-LayerNorm epilogue.
// N = 256 fixed; ldb = K (BT is [256][K]); ldc = 256.
// EPI 0: resid = fp32 src; output = bf16 x_bf  (G4 + LN1)
// EPI 1: resid = bf16 x;   output = fp32 d_out (G6 + LN2)
// 8 waves: wr = wid>>2 (2 row-bands), wc = wid&3 (4 col-bands of 64).
// ---------------------------------------------------------------------------
template <int EPI>
__global__ __launch_bounds__(512) void gemm_ln(const short* __restrict__ Ab,
                                               const short* __restrict__ BT,
                                               const float* __restrict__ bias,
                                               const void* __restrict__ resid,
                                               void* __restrict__ out,
                                               const float* __restrict__ g,
                                               const float* __restrict__ be,
                                               int M, int K) {
    const int t = threadIdx.x;
    const int m0 = blockIdx.x * 128;
    const int wid = t >> 6, lane = t & 63;
    const int wr = wid >> 2, wc = wid & 3;
    const int quad = lane >> 4, l16 = lane & 15;

    __shared__ short lA[2][128 * 32];
    __shared__ short lB[2][256 * 32];
    __shared__ float2 part[128][4];
    __shared__ float2 stats[128];

    f32x4 acc[4][4];
#pragma unroll
    for (int i = 0; i < 4; ++i)
#pragma unroll
        for (int j = 0; j < 4; ++j) acc[i][j] = (f32x4){0.f, 0.f, 0.f, 0.f};

    const int ga_row = wid * 16 + (lane >> 2);   // A: 16 rows per wave
    const int gb_row = wid * 32 + (lane >> 2);   // B: 32 rows per wave
    const int gcol8 = (lane & 3) * 8;
    auto stage = [&](int buf, int k0) {
        GLOAD16(Ab + (size_t)(m0 + ga_row) * K + k0 + gcol8,
                &lA[buf][(wid * 16) * 32]);
        GLOAD16(BT + (size_t)gb_row * K + k0 + gcol8,
                &lB[buf][(wid * 32) * 32]);
        GLOAD16(BT + (size_t)(gb_row + 16) * K + k0 + gcol8,
                &lB[buf][(wid * 32 + 16) * 32]);
    };
    stage(0, 0);
    __syncthreads();
    int cur = 0;
    for (int k0 = 0; k0 < K; k0 += 32) {
        if (k0 + 32 < K) stage(cur ^ 1, k0 + 32);
        short8 af[4], bfr[4];
#pragma unroll
        for (int mi = 0; mi < 4; ++mi)
            af[mi] = *(const short8*)&lA[cur][(wr * 64 + mi * 16 + l16) * 32 + quad * 8];
#pragma unroll
        for (int ni = 0; ni < 4; ++ni)
            bfr[ni] = *(const short8*)&lB[cur][(wc * 64 + ni * 16 + l16) * 32 + quad * 8];
#pragma unroll
        for (int mi = 0; mi < 4; ++mi)
#pragma unroll
            for (int ni = 0; ni < 4; ++ni)
                acc[mi][ni] = __builtin_amdgcn_mfma_f32_16x16x32_bf16(
                    af[mi], bfr[ni], acc[mi][ni], 0, 0, 0);
        __syncthreads();
        cur ^= 1;
    }

    // ---- epilogue: v = acc + bias + resid; row-LN over 256 cols ----
    float biasv[4], gv[4], bev[4];
    int gcs[4];
#pragma unroll
    for (int ni = 0; ni < 4; ++ni) {
        gcs[ni] = wc * 64 + ni * 16 + l16;
        biasv[ni] = bias[gcs[ni]];
        gv[ni] = g[gcs[ni]];
        bev[ni] = be[gcs[ni]];
    }
#pragma unroll
    for (int mi = 0; mi < 4; ++mi) {
#pragma unroll
        for (int r = 0; r < 4; ++r) {
            const int lr = wr * 64 + mi * 16 + quad * 4 + r;
            const int gr = m0 + lr;
            const bool ok = (gr < M);
            float s1 = 0.f, s2 = 0.f;
#pragma unroll
            for (int ni = 0; ni < 4; ++ni) {
                float v = acc[mi][ni][r] + biasv[ni];
                if (ok) {
                    if (EPI == 0)
                        v += ((const float*)resid)[(size_t)gr * 256 + gcs[ni]];
                    else
                        v += bf2f(((const short*)resid)[(size_t)gr * 256 + gcs[ni]]);
                }
                acc[mi][ni][r] = v;
                s1 += v;
                s2 += v * v;
            }
#pragma unroll
            for (int o = 1; o < 16; o <<= 1) {
                s1 += __shfl_xor(s1, o);
                s2 += __shfl_xor(s2, o);
            }
            if (l16 == 0) part[lr][wc] = make_float2(s1, s2);
        }
    }
    __syncthreads();
    if (t < 128) {
        float s1 = 0.f, s2 = 0.f;
#pragma unroll
        for (int w = 0; w < 4; ++w) {
            const float2 p = part[t][w];
            s1 += p.x;
            s2 += p.y;
        }
        const float mean = s1 * (1.0f / 256.0f);
        const float var = s2 * (1.0f / 256.0f) - mean * mean;
        stats[t] = make_float2(mean, rsqrtf(var + 1e-5f));
    }
    __syncthreads();
#pragma unroll
    for (int mi = 0; mi < 4; ++mi) {
#pragma unroll
        for (int r = 0; r < 4; ++r) {
            const int lr = wr * 64 + mi * 16 + quad * 4 + r;
            const int gr = m0 + lr;
            if (gr < M) {
                const float2 st = stats[lr];
#pragma unroll
                for (int ni = 0; ni < 4; ++ni) {
                    const float v = (acc[mi][ni][r] - st.x) * st.y * gv[ni] + bev[ni];
                    if (EPI == 0)
                        ((short*)out)[(size_t)gr * 256 + gcs[ni]] = f2bf(v);
                    else
                        ((float*)out)[(size_t)gr * 256 + gcs[ni]] = v;
                }
            }
        }
    }
}

// ---------------------------------------------------------------------------
// MS deformable sampling, head-major value [B][NH][LQ][HD].
// 16 threads per (row, head): thread = (level l, dimgroup sub).
// Cross-level sums via shfl_xor {4,8}. XCD-chunked bijective block swizzle.
// ---------------------------------------------------------------------------
__global__ __launch_bounds__(256) void sample_k(const short* __restrict__ value,
                                                const short* __restrict__ offaw,
                                                const float* __restrict__ refp,
                                                short* __restrict__ attn,
                                                int nwg) {
    int wg = blockIdx.x;
    {
        const int q = nwg >> 3, r = nwg & 7;
        const int xcd = wg & 7, idx = wg >> 3;
        wg = (xcd < r ? xcd * (q + 1) : r * (q + 1) + (xcd - r) * q) + idx;
    }
    const int tid = threadIdx.x;
    const int grp = wg * 16 + (tid >> 4);
    const int s16 = tid & 15;
    const int l = s16 >> 2, sub = s16 & 3;
    const int row = grp >> 3, h = grp & 7;
    const int b = row / LQn;
    const int L = (l == 0) ? 100 : (l == 1) ? 50 : (l == 2) ? 25 : 13;
    const int O = (l == 0) ? 0 : (l == 1) ? 10000 : (l == 2) ? 12500 : 13125;
    const float Lf = (float)L;

    const short* op = offaw + (size_t)row * 384 + h * 32;
    const short* ap = offaw + (size_t)row * 384 + 256 + h * 16;

    const short4v alog = *(const short4v*)(ap + l * 4);
    float lg[4];
#pragma unroll
    for (int j = 0; j < 4; ++j) lg[j] = bf2f(alog[j]);
    float m = fmaxf(fmaxf(lg[0], lg[1]), fmaxf(lg[2], lg[3]));
    m = fmaxf(m, __shfl_xor(m, 4));
    m = fmaxf(m, __shfl_xor(m, 8));
    float s = 0.f;
#pragma unroll
    for (int j = 0; j < 4; ++j) { lg[j] = __expf(lg[j] - m); s += lg[j]; }
    s += __shfl_xor(s, 4);
    s += __shfl_xor(s, 8);
    const float inv = 1.f / s;

    const float2 rxy = *(const float2*)(refp + (size_t)row * 8 + l * 2);
    const short8 ov = *(const short8*)(op + l * 8);
    const short* vlev = value + ((size_t)(b * 8 + h) * LQn + O) * 32 + sub * 8;

    float acc[8];
#pragma unroll
    for (int j = 0; j < 8; ++j) acc[j] = 0.f;

#pragma unroll 2
    for (int p = 0; p < 4; ++p) {
        const float x = fmaf(rxy.x, Lf, bf2f(ov[p * 2 + 0]) - 0.5f);
        const float y = fmaf(rxy.y, Lf, bf2f(ov[p * 2 + 1]) - 0.5f);
        const float xf = floorf(x), yf = floorf(y);
        const int ix = (int)xf, iy = (int)yf;
        const float fx = x - xf, fy = y - yf;
        const float aw = lg[p] * inv;
        const float vx0 = ((unsigned)ix < (unsigned)L) ? 1.f : 0.f;
        const float vx1 = ((unsigned)(ix + 1) < (unsigned)L) ? 1.f : 0.f;
        const float vy0 = ((unsigned)iy < (unsigned)L) ? 1.f : 0.f;
        const float vy1 = ((unsigned)(iy + 1) < (unsigned)L) ? 1.f : 0.f;
        const float gx0 = (1.f - fx) * aw, gx1 = fx * aw;
        const float w00 = gx0 * (1.f - fy) * vx0 * vy0;
        const float w10 = gx1 * (1.f - fy) * vx1 * vy0;
        const float w01 = gx0 * fy * vx0 * vy1;
        const float w11 = gx1 * fy * vx1 * vy1;
        const int ix0 = min(max(ix, 0), L - 1);
        const int ix1 = min(max(ix + 1, 0), L - 1);
        const int iy0 = min(max(iy, 0), L - 1);
        const int iy1 = min(max(iy + 1, 0), L - 1);
        const short8 v00 = *(const short8*)(vlev + ((size_t)iy0 * L + ix0) * 32);
        const short8 v10 = *(const short8*)(vlev + ((size_t)iy0 * L + ix1) * 32);
        const short8 v01 = *(const short8*)(vlev + ((size_t)iy1 * L + ix0) * 32);
        const short8 v11 = *(const short8*)(vlev + ((size_t)iy1 * L + ix1) * 32);
#pragma unroll
        for (int j = 0; j < 8; ++j)
            acc[j] += w00 * bf2f(v00[j]) + w10 * bf2f(v10[j]) +
                      w01 * bf2f(v01[j]) + w11 * bf2f(v11[j]);
    }

#pragma unroll
    for (int j = 0; j < 8; ++j) {
        acc[j] += __shfl_xor(acc[j], 4);
        acc[j] += __shfl_xor(acc[j], 8);
    }

    if (l == 0) {
        short8 o;
#pragma unroll
        for (int j = 0; j < 8; ++j) o[j] = f2bf(acc[j]);
        *(short8*)(attn + (size_t)row * 256 + h * 32 + sub * 8) = o;
    }
}

// ---------------------------------------------------------------------------
extern "C" void kernel_launch(void* const* d_in, const int* in_sizes, int n_in,
                              void* d_out, int out_size, void* d_ws, size_t ws_size,
                              hipStream_t stream) {
    (void)in_sizes; (void)n_in; (void)out_size; (void)ws_size;
    const float* src  = (const float*)d_in[0];
    const float* pos  = (const float*)d_in[1];
    const float* refp = (const float*)d_in[2];
    const float* Wv = (const float*)d_in[5];
    const float* bv = (const float*)d_in[6];
    const float* Ws = (const float*)d_in[7];
    const float* bs = (const float*)d_in[8];
    const float* Wa = (const float*)d_in[9];
    const float* ba = (const float*)d_in[10];
    const float* Wo = (const float*)d_in[11];
    const float* bo = (const float*)d_in[12];
    const float* W1 = (const float*)d_in[13];
    const float* b1 = (const float*)d_in[14];
    const float* W2 = (const float*)d_in[15];
    const float* b2 = (const float*)d_in[16];
    const float* g1 = (const float*)d_in[17];
    const float* be1 = (const float*)d_in[18];
    const float* g2 = (const float*)d_in[19];
    const float* be2 = (const float*)d_in[20];

    char* ws = (char*)d_ws;
    size_t off = 0;
    auto take = [&](size_t bytes) {
        char* p = ws + off;
        off += (bytes + 255) & ~(size_t)255;
        return p;
    };
    short* WvT  = (short*)take(256 * 256 * 2);
    short* WsaT = (short*)take(384 * 256 * 2);
    short* WoT  = (short*)take(256 * 256 * 2);
    short* W1T  = (short*)take(1024 * 256 * 2);
    short* W2T  = (short*)take(256 * 1024 * 2);
    float* bsa  = (float*)take(384 * 4);
    short* value_h = (short*)take((size_t)MP * 256 * 2);  // later x_bf
    short* offaw   = (short*)take((size_t)MP * 384 * 2);  // later h part 1
    short* attn_bf = (short*)take((size_t)MP * 256 * 2);  // q_bf / attn / h part 2
    // total ~96.9 MB

    short* q_bf = attn_bf;
    short* x_bf = value_h;
    short* h    = offaw;           // 26624 rows x 1024 cols bf16 = 54.5 MB
    float* z    = (float*)d_out;

    prep_all<<<2945, 256, 0, stream>>>(Wv, Ws, Wa, Wo, W1, W2, bs, ba,
                                       WvT, WsaT, WoT, W1T, W2T, bsa);
    make_q_k<<<(MREAL * 32 + 255) / 256, 256, 0, stream>>>(src, pos, q_bf,
                                                           MREAL * 32);
    // G1: value (head-major) = bf16(src) @ WvT + bv
    gemm_bt<1, 5><<<dim3(MT, 2), 256, 0, stream>>>(
        nullptr, src, WvT, bv, value_h, MREAL, 256, 256, 256, 256);
    // G2: offaw = q_bf @ WsaT + bsa
    gemm_bt<0, 1><<<dim3(MT, 3), 256, 0, stream>>>(
        q_bf, nullptr, WsaT, bsa, offaw, MREAL, 256, 384, 256, 384);
    // Deformable sampling
    {
        const int nwg = (MREAL * 8) / 16;  // 26588 blocks
        sample_k<<<nwg, 256, 0, stream>>>(value_h, offaw, refp, attn_bf, nwg);
    }
    // G4 + LN1 fused: x_bf = LN(src + attn @ WoT + bo)
    gemm_ln<0><<<MT, 512, 0, stream>>>(attn_bf, WoT, bo, src, x_bf, g1, be1,
                                       MREAL, 256);
    // FFN over two M-halves; G6 + LN2 fused
    for (int half = 0; half < 2; ++half) {
        const size_t ro = (size_t)half * MHALF;
        gemm_bt<0, 2><<<dim3(MTH, 8), 256, 0, stream>>>(
            x_bf + ro * 256, nullptr, W1T, b1, h, MHALF, 256, 1024, 256, 1024);
        gemm_ln<1><<<MTH, 512, 0, stream>>>(h, W2T, b2, x_bf + ro * 256,
                                            z + ro * 256, g2, be2, MHALF, 1024);
    }
}

// Round 10
// 442.310 us; speedup vs baseline: 2.7943x; 1.0344x over previous
//
#include <hip/hip_runtime.h>

// ---------------------------------------------------------------------------
// DeformableTransformerEncoderLayer on MI355X (gfx950)
// B=4, LQ=13294, DM=256, DFFN=1024, NL=4, NH=8, NP=4, HD=32
// M = 53176 rows, padded tiles to Mp = 53248 = 416*128.
// Round 10:
//  - sample_k: 32-bit corner address math (row offsets reused; no 64-bit mul)
//  - gemm_bt: XCD-aware bijective swizzle putting the NT blocks that share
//    one A-tile consecutively on ONE XCD (A-reads become L2 hits).
//  - make_q merged into prep_all (8 dispatches total).
// Pipeline:
//   prep_all (+q_bf); G1 value_h; G2 offaw; sample; G4LN x_bf;
//   2x { G5 h; G6LN d_out }
// ---------------------------------------------------------------------------

#define LQn   13294
#define MREAL 53176
#define MP    53248
#define MT    416
#define MHALF 26588
#define MTH   208

typedef __attribute__((ext_vector_type(8))) short short8;
typedef __attribute__((ext_vector_type(4))) short short4v;
typedef __attribute__((ext_vector_type(4))) float f32x4;

__device__ __forceinline__ short f2bf(float f) {
    unsigned u = __float_as_uint(f);
    unsigned r = (u + 0x7FFFu + ((u >> 16) & 1u)) >> 16;  // RNE
    return (short)r;
}
__device__ __forceinline__ float bf2f(short b) {
    return __uint_as_float(((unsigned)(unsigned short)b) << 16);
}

#define GLOAD16(gp, lp)                                                        \
    __builtin_amdgcn_global_load_lds(                                          \
        (const __attribute__((address_space(1))) void*)(gp),                   \
        (__attribute__((address_space(3))) void*)(lp), 16, 0, 0)

// ---------------------------------------------------------------------------
// Weight prep + bias concat + q_bf=bf16(src+pos), all in ONE dispatch.
// blocks [0,2944): transposes; 2944: bias; [2945, 9593): make_q.
// ---------------------------------------------------------------------------
__global__ __launch_bounds__(256) void prep_all(
    const float* __restrict__ Wv, const float* __restrict__ Ws,
    const float* __restrict__ Wa, const float* __restrict__ Wo,
    const float* __restrict__ W1, const float* __restrict__ W2,
    const float* __restrict__ bs, const float* __restrict__ ba,
    const float* __restrict__ src, const float* __restrict__ pos,
    short* __restrict__ WvT, short* __restrict__ WsaT,
    short* __restrict__ WoT, short* __restrict__ W1T,
    short* __restrict__ W2T, float* __restrict__ bsa,
    short* __restrict__ q_bf) {
    const int bid = blockIdx.x, tid = threadIdx.x;
    if (bid >= 2945) {
        const int i = (bid - 2945) * 256 + tid;
        if (i < MREAL * 32) {
            const float4 a0 = ((const float4*)src)[i * 2];
            const float4 a1 = ((const float4*)src)[i * 2 + 1];
            const float4 b0 = ((const float4*)pos)[i * 2];
            const float4 b1 = ((const float4*)pos)[i * 2 + 1];
            short8 o;
            o[0] = f2bf(a0.x + b0.x); o[1] = f2bf(a0.y + b0.y);
            o[2] = f2bf(a0.z + b0.z); o[3] = f2bf(a0.w + b0.w);
            o[4] = f2bf(a1.x + b1.x); o[5] = f2bf(a1.y + b1.y);
            o[6] = f2bf(a1.z + b1.z); o[7] = f2bf(a1.w + b1.w);
            ((short8*)q_bf)[i] = o;
        }
        return;
    }
    const float* W; short* WT; int K, N, base;
    if (bid < 256)       { W = Wv; WT = WvT;              K = 256;  N = 256;  base = 0; }
    else if (bid < 512)  { W = Ws; WT = WsaT;             K = 256;  N = 256;  base = 256; }
    else if (bid < 640)  { W = Wa; WT = WsaT + 256 * 256; K = 256;  N = 128;  base = 512; }
    else if (bid < 896)  { W = Wo; WT = WoT;              K = 256;  N = 256;  base = 640; }
    else if (bid < 1920) { W = W1; WT = W1T;              K = 256;  N = 1024; base = 896; }
    else if (bid < 2944) { W = W2; WT = W2T;              K = 1024; N = 256;  base = 1920; }
    else {
        if (tid < 256) bsa[tid] = bs[tid];
        else if (tid < 384) bsa[tid] = ba[tid - 256];
        return;
    }
    const int i = (bid - base) * 256 + tid;
    const int n = i / K, k = i - n * K;
    WT[i] = f2bf(W[(size_t)k * N + n]);
}

// ---------------------------------------------------------------------------
// bf16 MFMA GEMM. 128x128 tile, BK=32, 4 waves, 16x16x32 MFMA.
// 1-D grid of NT * Mtiles blocks. XCD-aware bijective swizzle: the NT blocks
// sharing an A-tile run consecutively on one XCD (A L2-resident).
// SRC: 0 = A bf16, dbuf global_load_lds; 1 = A fp32 (convert, reg staging)
// EPI: 1 = bf16+bias; 2 = relu->bf16+bias; 5 = bf16+bias scattered head-major
// ---------------------------------------------------------------------------
template <int SRC, int EPI, int NT>
__global__ __launch_bounds__(256) void gemm_bt(const short* __restrict__ Ab,
                                               const float* __restrict__ Af,
                                               const short* __restrict__ BT,
                                               const float* __restrict__ bias,
                                               void* C,
                                               int M, int K, int N,
                                               int ldb, int ldc) {
    const int d = blockIdx.x;
    const int c = d & 7, j = d >> 3;
    const int jg = j / NT;
    const int m0 = (c + 8 * jg) * 128;
    const int n0 = (j - jg * NT) * 128;
    const int t = threadIdx.x;
    const int wid = t >> 6, lane = t & 63;
    const int wr = wid >> 1, wc = wid & 1;
    const int quad = lane >> 4, l16 = lane & 15;

    f32x4 acc[4][4];
#pragma unroll
    for (int i = 0; i < 4; ++i)
#pragma unroll
        for (int jj = 0; jj < 4; ++jj) acc[i][jj] = (f32x4){0.f, 0.f, 0.f, 0.f};

    if constexpr (SRC == 0) {
        __shared__ short lA[2][128 * 32];
        __shared__ short lB[2][128 * 32];
        const int grow = wid * 32 + (lane >> 2);
        const int gcol = (lane & 3) * 8;
        auto stage = [&](int buf, int k0) {
            GLOAD16(Ab + (size_t)(m0 + grow) * K + k0 + gcol,
                    &lA[buf][(wid * 32) * 32]);
            GLOAD16(Ab + (size_t)(m0 + grow + 16) * K + k0 + gcol,
                    &lA[buf][(wid * 32 + 16) * 32]);
            GLOAD16(BT + (size_t)(n0 + grow) * ldb + k0 + gcol,
                    &lB[buf][(wid * 32) * 32]);
            GLOAD16(BT + (size_t)(n0 + grow + 16) * ldb + k0 + gcol,
                    &lB[buf][(wid * 32 + 16) * 32]);
        };
        stage(0, 0);
        __syncthreads();
        int cur = 0;
        for (int k0 = 0; k0 < K; k0 += 32) {
            if (k0 + 32 < K) stage(cur ^ 1, k0 + 32);
            short8 af[4], bfr[4];
#pragma unroll
            for (int mi = 0; mi < 4; ++mi)
                af[mi] = *(const short8*)&lA[cur][(wr * 64 + mi * 16 + l16) * 32 + quad * 8];
#pragma unroll
            for (int ni = 0; ni < 4; ++ni)
                bfr[ni] = *(const short8*)&lB[cur][(wc * 64 + ni * 16 + l16) * 32 + quad * 8];
#pragma unroll
            for (int mi = 0; mi < 4; ++mi)
#pragma unroll
                for (int ni = 0; ni < 4; ++ni)
                    acc[mi][ni] = __builtin_amdgcn_mfma_f32_16x16x32_bf16(
                        af[mi], bfr[ni], acc[mi][ni], 0, 0, 0);
            __syncthreads();
            cur ^= 1;
        }
    } else {
        __shared__ short lA[128 * 32];
        __shared__ short lB[128 * 32];
        const int ar0 = t >> 2, ac0 = (t & 3) * 8;
        const int ar1 = ar0 + 64, ac1 = ac0;
        const int arow0 = min(m0 + ar0, M - 1);
        const int arow1 = min(m0 + ar1, M - 1);
        for (int k0 = 0; k0 < K; k0 += 32) {
            short8 va0, va1;
            {
                const size_t i0 = (size_t)arow0 * K + k0 + ac0;
                const size_t i1 = (size_t)arow1 * K + k0 + ac1;
                const float4 l0 = *(const float4*)(Af + i0);
                const float4 h0 = *(const float4*)(Af + i0 + 4);
                const float4 l1 = *(const float4*)(Af + i1);
                const float4 h1 = *(const float4*)(Af + i1 + 4);
                va0[0] = f2bf(l0.x); va0[1] = f2bf(l0.y); va0[2] = f2bf(l0.z);
                va0[3] = f2bf(l0.w); va0[4] = f2bf(h0.x); va0[5] = f2bf(h0.y);
                va0[6] = f2bf(h0.z); va0[7] = f2bf(h0.w);
                va1[0] = f2bf(l1.x); va1[1] = f2bf(l1.y); va1[2] = f2bf(l1.z);
                va1[3] = f2bf(l1.w); va1[4] = f2bf(h1.x); va1[5] = f2bf(h1.y);
                va1[6] = f2bf(h1.z); va1[7] = f2bf(h1.w);
            }
            const short8 vb0 = *(const short8*)(BT + (size_t)(n0 + ar0) * ldb + k0 + ac0);
            const short8 vb1 = *(const short8*)(BT + (size_t)(n0 + ar1) * ldb + k0 + ac1);
            __syncthreads();
            *(short8*)&lA[ar0 * 32 + ac0] = va0;
            *(short8*)&lA[ar1 * 32 + ac1] = va1;
            *(short8*)&lB[ar0 * 32 + ac0] = vb0;
            *(short8*)&lB[ar1 * 32 + ac1] = vb1;
            __syncthreads();
            short8 af[4], bfr[4];
#pragma unroll
            for (int mi = 0; mi < 4; ++mi)
                af[mi] = *(const short8*)&lA[(wr * 64 + mi * 16 + l16) * 32 + quad * 8];
#pragma unroll
            for (int ni = 0; ni < 4; ++ni)
                bfr[ni] = *(const short8*)&lB[(wc * 64 + ni * 16 + l16) * 32 + quad * 8];
#pragma unroll
            for (int mi = 0; mi < 4; ++mi)
#pragma unroll
                for (int ni = 0; ni < 4; ++ni)
                    acc[mi][ni] = __builtin_amdgcn_mfma_f32_16x16x32_bf16(
                        af[mi], bfr[ni], acc[mi][ni], 0, 0, 0);
        }
    }

#pragma unroll
    for (int ni = 0; ni < 4; ++ni) {
        const int gc = n0 + wc * 64 + ni * 16 + l16;
        const float bia = bias[gc];
#pragma unroll
        for (int mi = 0; mi < 4; ++mi) {
#pragma unroll
            for (int r = 0; r < 4; ++r) {
                const int gr = m0 + wr * 64 + mi * 16 + quad * 4 + r;
                if (gr < M) {
                    float v = acc[mi][ni][r] + bia;
                    if (EPI == 5) {
                        const int b = gr / LQn, s = gr - b * LQn;
                        const int hh = gc >> 5, dd = gc & 31;
                        ((short*)C)[(((size_t)b * 8 + hh) * LQn + s) * 32 + dd] = f2bf(v);
                    } else {
                        if (EPI == 2) v = fmaxf(v, 0.f);
                        ((short*)C)[(size_t)gr * ldc + gc] = f2bf(v);
                    }
                }
            }
        }
    }
}

// ---------------------------------------------------------------------------
// 512-thread 128x256-tile GEMM with fused row-LayerNorm epilogue.
// EPI 0: resid = fp32 src; output = bf16 x_bf  (G4 + LN1)
// EPI 1: resid = bf16 x;   output = fp32 d_out (G6 + LN2)
// ---------------------------------------------------------------------------
template <int EPI>
__global__ __launch_bounds__(512) void gemm_ln(const short* __restrict__ Ab,
                                               const short* __restrict__ BT,
                                               const float* __restrict__ bias,
                                               const void* __restrict__ resid,
                                               void* __restrict__ out,
                                               const float* __restrict__ g,
                                               const float* __restrict__ be,
                                               int M, int K) {
    const int t = threadIdx.x;
    const int m0 = blockIdx.x * 128;
    const int wid = t >> 6, lane = t & 63;
    const int wr = wid >> 2, wc = wid & 3;
    const int quad = lane >> 4, l16 = lane & 15;

    __shared__ short lA[2][128 * 32];
    __shared__ short lB[2][256 * 32];
    __shared__ float2 part[128][4];
    __shared__ float2 stats[128];

    f32x4 acc[4][4];
#pragma unroll
    for (int i = 0; i < 4; ++i)
#pragma unroll
        for (int j = 0; j < 4; ++j) acc[i][j] = (f32x4){0.f, 0.f, 0.f, 0.f};

    const int ga_row = wid * 16 + (lane >> 2);
    const int gb_row = wid * 32 + (lane >> 2);
    const int gcol8 = (lane & 3) * 8;
    auto stage = [&](int buf, int k0) {
        GLOAD16(Ab + (size_t)(m0 + ga_row) * K + k0 + gcol8,
                &lA[buf][(wid * 16) * 32]);
        GLOAD16(BT + (size_t)gb_row * K + k0 + gcol8,
                &lB[buf][(wid * 32) * 32]);
        GLOAD16(BT + (size_t)(gb_row + 16) * K + k0 + gcol8,
                &lB[buf][(wid * 32 + 16) * 32]);
    };
    stage(0, 0);
    __syncthreads();
    int cur = 0;
    for (int k0 = 0; k0 < K; k0 += 32) {
        if (k0 + 32 < K) stage(cur ^ 1, k0 + 32);
        short8 af[4], bfr[4];
#pragma unroll
        for (int mi = 0; mi < 4; ++mi)
            af[mi] = *(const short8*)&lA[cur][(wr * 64 + mi * 16 + l16) * 32 + quad * 8];
#pragma unroll
        for (int ni = 0; ni < 4; ++ni)
            bfr[ni] = *(const short8*)&lB[cur][(wc * 64 + ni * 16 + l16) * 32 + quad * 8];
#pragma unroll
        for (int mi = 0; mi < 4; ++mi)
#pragma unroll
            for (int ni = 0; ni < 4; ++ni)
                acc[mi][ni] = __builtin_amdgcn_mfma_f32_16x16x32_bf16(
                    af[mi], bfr[ni], acc[mi][ni], 0, 0, 0);
        __syncthreads();
        cur ^= 1;
    }

    float biasv[4], gv[4], bev[4];
    int gcs[4];
#pragma unroll
    for (int ni = 0; ni < 4; ++ni) {
        gcs[ni] = wc * 64 + ni * 16 + l16;
        biasv[ni] = bias[gcs[ni]];
        gv[ni] = g[gcs[ni]];
        bev[ni] = be[gcs[ni]];
    }
#pragma unroll
    for (int mi = 0; mi < 4; ++mi) {
#pragma unroll
        for (int r = 0; r < 4; ++r) {
            const int lr = wr * 64 + mi * 16 + quad * 4 + r;
            const int gr = m0 + lr;
            const bool ok = (gr < M);
            float s1 = 0.f, s2 = 0.f;
#pragma unroll
            for (int ni = 0; ni < 4; ++ni) {
                float v = acc[mi][ni][r] + biasv[ni];
                if (ok) {
                    if (EPI == 0)
                        v += ((const float*)resid)[(size_t)gr * 256 + gcs[ni]];
                    else
                        v += bf2f(((const short*)resid)[(size_t)gr * 256 + gcs[ni]]);
                }
                acc[mi][ni][r] = v;
                s1 += v;
                s2 += v * v;
            }
#pragma unroll
            for (int o = 1; o < 16; o <<= 1) {
                s1 += __shfl_xor(s1, o);
                s2 += __shfl_xor(s2, o);
            }
            if (l16 == 0) part[lr][wc] = make_float2(s1, s2);
        }
    }
    __syncthreads();
    if (t < 128) {
        float s1 = 0.f, s2 = 0.f;
#pragma unroll
        for (int w = 0; w < 4; ++w) {
            const float2 p = part[t][w];
            s1 += p.x;
            s2 += p.y;
        }
        const float mean = s1 * (1.0f / 256.0f);
        const float var = s2 * (1.0f / 256.0f) - mean * mean;
        stats[t] = make_float2(mean, rsqrtf(var + 1e-5f));
    }
    __syncthreads();
#pragma unroll
    for (int mi = 0; mi < 4; ++mi) {
#pragma unroll
        for (int r = 0; r < 4; ++r) {
            const int lr = wr * 64 + mi * 16 + quad * 4 + r;
            const int gr = m0 + lr;
            if (gr < M) {
                const float2 st = stats[lr];
#pragma unroll
                for (int ni = 0; ni < 4; ++ni) {
                    const float v = (acc[mi][ni][r] - st.x) * st.y * gv[ni] + bev[ni];
                    if (EPI == 0)
                        ((short*)out)[(size_t)gr * 256 + gcs[ni]] = f2bf(v);
                    else
                        ((float*)out)[(size_t)gr * 256 + gcs[ni]] = v;
                }
            }
        }
    }
}

// ---------------------------------------------------------------------------
// MS deformable sampling, head-major value [B][NH][LQ][HD].
// 16 threads per (row, head). 32-bit corner addressing (row offsets reused).
// ---------------------------------------------------------------------------
__global__ __launch_bounds__(256) void sample_k(const short* __restrict__ value,
                                                const short* __restrict__ offaw,
                                                const float* __restrict__ refp,
                                                short* __restrict__ attn,
                                                int nwg) {
    int wg = blockIdx.x;
    {
        const int q = nwg >> 3, r = nwg & 7;
        const int xcd = wg & 7, idx = wg >> 3;
        wg = (xcd < r ? xcd * (q + 1) : r * (q + 1) + (xcd - r) * q) + idx;
    }
    const int tid = threadIdx.x;
    const int grp = wg * 16 + (tid >> 4);
    const int s16 = tid & 15;
    const int l = s16 >> 2, sub = s16 & 3;
    const int row = grp >> 3, h = grp & 7;
    const int b = row / LQn;
    const int L = (l == 0) ? 100 : (l == 1) ? 50 : (l == 2) ? 25 : 13;
    const int O = (l == 0) ? 0 : (l == 1) ? 10000 : (l == 2) ? 12500 : 13125;
    const float Lf = (float)L;

    const short* op = offaw + (size_t)row * 384 + h * 32;
    const short* ap = offaw + (size_t)row * 384 + 256 + h * 16;

    const short4v alog = *(const short4v*)(ap + l * 4);
    float lg[4];
#pragma unroll
    for (int j = 0; j < 4; ++j) lg[j] = bf2f(alog[j]);
    float m = fmaxf(fmaxf(lg[0], lg[1]), fmaxf(lg[2], lg[3]));
    m = fmaxf(m, __shfl_xor(m, 4));
    m = fmaxf(m, __shfl_xor(m, 8));
    float s = 0.f;
#pragma unroll
    for (int j = 0; j < 4; ++j) { lg[j] = __expf(lg[j] - m); s += lg[j]; }
    s += __shfl_xor(s, 4);
    s += __shfl_xor(s, 8);
    const float inv = 1.f / s;

    const float2 rxy = *(const float2*)(refp + (size_t)row * 8 + l * 2);
    const short8 ov = *(const short8*)(op + l * 8);
    const short* vlev = value + ((size_t)(b * 8 + h) * LQn + O) * 32 + sub * 8;

    float acc[8];
#pragma unroll
    for (int j = 0; j < 8; ++j) acc[j] = 0.f;

#pragma unroll 2
    for (int p = 0; p < 4; ++p) {
        const float x = fmaf(rxy.x, Lf, bf2f(ov[p * 2 + 0]) - 0.5f);
        const float y = fmaf(rxy.y, Lf, bf2f(ov[p * 2 + 1]) - 0.5f);
        const float xf = floorf(x), yf = floorf(y);
        const int ix = (int)xf, iy = (int)yf;
        const float fx = x - xf, fy = y - yf;
        const float aw = lg[p] * inv;
        const float vx0 = ((unsigned)ix < (unsigned)L) ? 1.f : 0.f;
        const float vx1 = ((unsigned)(ix + 1) < (unsigned)L) ? 1.f : 0.f;
        const float vy0 = ((unsigned)iy < (unsigned)L) ? 1.f : 0.f;
        const float vy1 = ((unsigned)(iy + 1) < (unsigned)L) ? 1.f : 0.f;
        const float gx0 = (1.f - fx) * aw, gx1 = fx * aw;
        const float w00 = gx0 * (1.f - fy) * vx0 * vy0;
        const float w10 = gx1 * (1.f - fy) * vx1 * vy0;
        const float w01 = gx0 * fy * vx0 * vy1;
        const float w11 = gx1 * fy * vx1 * vy1;
        const int ix0 = min(max(ix, 0), L - 1);
        const int ix1 = min(max(ix + 1, 0), L - 1);
        const int iy0 = min(max(iy, 0), L - 1);
        const int iy1 = min(max(iy + 1, 0), L - 1);
        // 32-bit offsets; row products reused by both x-corners
        const int ro0 = iy0 * L, ro1 = iy1 * L;
        const short8 v00 = *(const short8*)(vlev + ((ro0 + ix0) << 5));
        const short8 v10 = *(const short8*)(vlev + ((ro0 + ix1) << 5));
        const short8 v01 = *(const short8*)(vlev + ((ro1 + ix0) << 5));
        const short8 v11 = *(const short8*)(vlev + ((ro1 + ix1) << 5));
#pragma unroll
        for (int j = 0; j < 8; ++j)
            acc[j] += w00 * bf2f(v00[j]) + w10 * bf2f(v10[j]) +
                      w01 * bf2f(v01[j]) + w11 * bf2f(v11[j]);
    }

#pragma unroll
    for (int j = 0; j < 8; ++j) {
        acc[j] += __shfl_xor(acc[j], 4);
        acc[j] += __shfl_xor(acc[j], 8);
    }

    if (l == 0) {
        short8 o;
#pragma unroll
        for (int j = 0; j < 8; ++j) o[j] = f2bf(acc[j]);
        *(short8*)(attn + (size_t)row * 256 + h * 32 + sub * 8) = o;
    }
}

// ---------------------------------------------------------------------------
extern "C" void kernel_launch(void* const* d_in, const int* in_sizes, int n_in,
                              void* d_out, int out_size, void* d_ws, size_t ws_size,
                              hipStream_t stream) {
    (void)in_sizes; (void)n_in; (void)out_size; (void)ws_size;
    const float* src  = (const float*)d_in[0];
    const float* pos  = (const float*)d_in[1];
    const float* refp = (const float*)d_in[2];
    const float* Wv = (const float*)d_in[5];
    const float* bv = (const float*)d_in[6];
    const float* Ws = (const float*)d_in[7];
    const float* bs = (const float*)d_in[8];
    const float* Wa = (const float*)d_in[9];
    const float* ba = (const float*)d_in[10];
    const float* Wo = (const float*)d_in[11];
    const float* bo = (const float*)d_in[12];
    const float* W1 = (const float*)d_in[13];
    const float* b1 = (const float*)d_in[14];
    const float* W2 = (const float*)d_in[15];
    const float* b2 = (const float*)d_in[16];
    const float* g1 = (const float*)d_in[17];
    const float* be1 = (const float*)d_in[18];
    const float* g2 = (const float*)d_in[19];
    const float* be2 = (const float*)d_in[20];

    char* ws = (char*)d_ws;
    size_t off = 0;
    auto take = [&](size_t bytes) {
        char* p = ws + off;
        off += (bytes + 255) & ~(size_t)255;
        return p;
    };
    short* WvT  = (short*)take(256 * 256 * 2);
    short* WsaT = (short*)take(384 * 256 * 2);
    short* WoT  = (short*)take(256 * 256 * 2);
    short* W1T  = (short*)take(1024 * 256 * 2);
    short* W2T  = (short*)take(256 * 1024 * 2);
    float* bsa  = (float*)take(384 * 4);
    short* value_h = (short*)take((size_t)MP * 256 * 2);  // later x_bf
    short* offaw   = (short*)take((size_t)MP * 384 * 2);  // later h part 1
    short* attn_bf = (short*)take((size_t)MP * 256 * 2);  // q_bf / attn / h part 2
    // total ~96.9 MB

    short* q_bf = attn_bf;
    short* x_bf = value_h;
    short* h    = offaw;
    float* z    = (float*)d_out;

    prep_all<<<9593, 256, 0, stream>>>(Wv, Ws, Wa, Wo, W1, W2, bs, ba, src, pos,
                                       WvT, WsaT, WoT, W1T, W2T, bsa, q_bf);
    // G1: value (head-major) = bf16(src) @ WvT + bv   (NT=2, 832 blocks)
    gemm_bt<1, 5, 2><<<832, 256, 0, stream>>>(
        nullptr, src, WvT, bv, value_h, MREAL, 256, 256, 256, 256);
    // G2: offaw = q_bf @ WsaT + bsa                   (NT=3, 1248 blocks)
    gemm_bt<0, 1, 3><<<1248, 256, 0, stream>>>(
        q_bf, nullptr, WsaT, bsa, offaw, MREAL, 256, 384, 256, 384);
    // Deformable sampling
    {
        const int nwg = (MREAL * 8) / 16;  // 26588 blocks
        sample_k<<<nwg, 256, 0, stream>>>(value_h, offaw, refp, attn_bf, nwg);
    }
    // G4 + LN1 fused: x_bf = LN(src + attn @ WoT + bo)
    gemm_ln<0><<<MT, 512, 0, stream>>>(attn_bf, WoT, bo, src, x_bf, g1, be1,
                                       MREAL, 256);
    // FFN over two M-halves; G6 + LN2 fused
    for (int half = 0; half < 2; ++half) {
        const size_t ro = (size_t)half * MHALF;
        gemm_bt<0, 2, 8><<<1664, 256, 0, stream>>>(
            x_bf + ro * 256, nullptr, W1T, b1, h, MHALF, 256, 1024, 256, 1024);
        gemm_ln<1><<<MTH, 512, 0, stream>>>(h, W2T, b2, x_bf + ro * 256,
                                            z + ro * 256, g2, be2, MHALF, 1024);
    }
}

// Round 11
// 414.394 us; speedup vs baseline: 2.9825x; 1.0674x over previous
//
#include <hip/hip_runtime.h>

// ---------------------------------------------------------------------------
// DeformableTransformerEncoderLayer on MI355X (gfx950)
// B=4, LQ=13294, DM=256, DFFN=1024, NL=4, NH=8, NP=4, HD=32
// M = 53176 rows, padded tiles to Mp = 53248 = 416*128.
// Round 11:
//  - prep_all also emits src_bf; G1 uses the dbuf gload path (bf16 A).
//    If ws_size allows, src_bf is persistent and G4LN's residual is bf16.
//  - LDS-bounce vectorized epilogue (short8 stores, XOR-swizzled LDS) for
//    gemm_bt (all EPIs) and gemm_ln bf16 output.
// Pipeline (9 dispatches):
//   prep_all (+q_bf,+src_bf); G1 value_h; G2 offaw; sample; G4LN x_bf;
//   2x { G5 h; G6LN d_out }
// ---------------------------------------------------------------------------

#define LQn   13294
#define MREAL 53176
#define MP    53248
#define MT    416
#define MHALF 26588
#define MTH   208

typedef __attribute__((ext_vector_type(8))) short short8;
typedef __attribute__((ext_vector_type(4))) short short4v;
typedef __attribute__((ext_vector_type(4))) float f32x4;

__device__ __forceinline__ short f2bf(float f) {
    unsigned u = __float_as_uint(f);
    unsigned r = (u + 0x7FFFu + ((u >> 16) & 1u)) >> 16;  // RNE
    return (short)r;
}
__device__ __forceinline__ float bf2f(short b) {
    return __uint_as_float(((unsigned)(unsigned short)b) << 16);
}

#define GLOAD16(gp, lp)                                                        \
    __builtin_amdgcn_global_load_lds(                                          \
        (const __attribute__((address_space(1))) void*)(gp),                   \
        (__attribute__((address_space(3))) void*)(lp), 16, 0, 0)

// ---------------------------------------------------------------------------
// Weight prep + bias concat + q_bf / src_bf, all in ONE dispatch.
// blocks [0,2944): transposes; 2944: bias; [2945, 9593): q/src convert.
// ---------------------------------------------------------------------------
__global__ __launch_bounds__(256) void prep_all(
    const float* __restrict__ Wv, const float* __restrict__ Ws,
    const float* __restrict__ Wa, const float* __restrict__ Wo,
    const float* __restrict__ W1, const float* __restrict__ W2,
    const float* __restrict__ bs, const float* __restrict__ ba,
    const float* __restrict__ src, const float* __restrict__ pos,
    short* __restrict__ WvT, short* __restrict__ WsaT,
    short* __restrict__ WoT, short* __restrict__ W1T,
    short* __restrict__ W2T, float* __restrict__ bsa,
    short* __restrict__ q_bf, short* __restrict__ src_bf) {
    const int bid = blockIdx.x, tid = threadIdx.x;
    if (bid >= 2945) {
        const int i = (bid - 2945) * 256 + tid;
        if (i < MREAL * 32) {
            const float4 a0 = ((const float4*)src)[i * 2];
            const float4 a1 = ((const float4*)src)[i * 2 + 1];
            const float4 b0 = ((const float4*)pos)[i * 2];
            const float4 b1 = ((const float4*)pos)[i * 2 + 1];
            short8 o, o2;
            o[0] = f2bf(a0.x + b0.x); o[1] = f2bf(a0.y + b0.y);
            o[2] = f2bf(a0.z + b0.z); o[3] = f2bf(a0.w + b0.w);
            o[4] = f2bf(a1.x + b1.x); o[5] = f2bf(a1.y + b1.y);
            o[6] = f2bf(a1.z + b1.z); o[7] = f2bf(a1.w + b1.w);
            o2[0] = f2bf(a0.x); o2[1] = f2bf(a0.y);
            o2[2] = f2bf(a0.z); o2[3] = f2bf(a0.w);
            o2[4] = f2bf(a1.x); o2[5] = f2bf(a1.y);
            o2[6] = f2bf(a1.z); o2[7] = f2bf(a1.w);
            ((short8*)q_bf)[i] = o;
            ((short8*)src_bf)[i] = o2;
        }
        return;
    }
    const float* W; short* WT; int K, N, base;
    if (bid < 256)       { W = Wv; WT = WvT;              K = 256;  N = 256;  base = 0; }
    else if (bid < 512)  { W = Ws; WT = WsaT;             K = 256;  N = 256;  base = 256; }
    else if (bid < 640)  { W = Wa; WT = WsaT + 256 * 256; K = 256;  N = 128;  base = 512; }
    else if (bid < 896)  { W = Wo; WT = WoT;              K = 256;  N = 256;  base = 640; }
    else if (bid < 1920) { W = W1; WT = W1T;              K = 256;  N = 1024; base = 896; }
    else if (bid < 2944) { W = W2; WT = W2T;              K = 1024; N = 256;  base = 1920; }
    else {
        if (tid < 256) bsa[tid] = bs[tid];
        else if (tid < 384) bsa[tid] = ba[tid - 256];
        return;
    }
    const int i = (bid - base) * 256 + tid;
    const int n = i / K, k = i - n * K;
    WT[i] = f2bf(W[(size_t)k * N + n]);
}

// ---------------------------------------------------------------------------
// bf16 MFMA GEMM. 128x128 tile, BK=32, 4 waves, 16x16x32 MFMA.
// Dbuf global_load_lds staging; NT-swizzled 1-D grid (A-tile L2 locality).
// Vectorized LDS-bounce epilogue (short8 stores).
// EPI: 1 = bf16+bias; 2 = relu->bf16+bias; 5 = bf16+bias head-major scatter
// ---------------------------------------------------------------------------
template <int EPI, int NT>
__global__ __launch_bounds__(256) void gemm_bt(const short* __restrict__ Ab,
                                               const short* __restrict__ BT,
                                               const float* __restrict__ bias,
                                               void* C,
                                               int M, int K, int N,
                                               int ldb, int ldc) {
    const int d = blockIdx.x;
    const int c = d & 7, j = d >> 3;
    const int jg = j / NT;
    const int m0 = (c + 8 * jg) * 128;
    const int n0 = (j - jg * NT) * 128;
    const int t = threadIdx.x;
    const int wid = t >> 6, lane = t & 63;
    const int wr = wid >> 1, wc = wid & 1;
    const int quad = lane >> 4, l16 = lane & 15;

    __shared__ short lA[2][128 * 32];
    __shared__ short lB[2][128 * 32];

    f32x4 acc[4][4];
#pragma unroll
    for (int i = 0; i < 4; ++i)
#pragma unroll
        for (int jj = 0; jj < 4; ++jj) acc[i][jj] = (f32x4){0.f, 0.f, 0.f, 0.f};

    const int grow = wid * 32 + (lane >> 2);
    const int gcol = (lane & 3) * 8;
    auto stage = [&](int buf, int k0) {
        GLOAD16(Ab + (size_t)(m0 + grow) * K + k0 + gcol,
                &lA[buf][(wid * 32) * 32]);
        GLOAD16(Ab + (size_t)(m0 + grow + 16) * K + k0 + gcol,
                &lA[buf][(wid * 32 + 16) * 32]);
        GLOAD16(BT + (size_t)(n0 + grow) * ldb + k0 + gcol,
                &lB[buf][(wid * 32) * 32]);
        GLOAD16(BT + (size_t)(n0 + grow + 16) * ldb + k0 + gcol,
                &lB[buf][(wid * 32 + 16) * 32]);
    };
    stage(0, 0);
    __syncthreads();
    int cur = 0;
    for (int k0 = 0; k0 < K; k0 += 32) {
        if (k0 + 32 < K) stage(cur ^ 1, k0 + 32);
        short8 af[4], bfr[4];
#pragma unroll
        for (int mi = 0; mi < 4; ++mi)
            af[mi] = *(const short8*)&lA[cur][(wr * 64 + mi * 16 + l16) * 32 + quad * 8];
#pragma unroll
        for (int ni = 0; ni < 4; ++ni)
            bfr[ni] = *(const short8*)&lB[cur][(wc * 64 + ni * 16 + l16) * 32 + quad * 8];
#pragma unroll
        for (int mi = 0; mi < 4; ++mi)
#pragma unroll
            for (int ni = 0; ni < 4; ++ni)
                acc[mi][ni] = __builtin_amdgcn_mfma_f32_16x16x32_bf16(
                    af[mi], bfr[ni], acc[mi][ni], 0, 0, 0);
        __syncthreads();
        cur ^= 1;
    }

    // ---- LDS-bounce vectorized epilogue: 2 passes of 64 cols ----
    short* lflat = (short*)lA;  // 8192 shorts = 128 x 64
#pragma unroll
    for (int p = 0; p < 2; ++p) {
        if (wc == p) {
#pragma unroll
            for (int ni = 0; ni < 4; ++ni) {
                const int lc = ni * 16 + l16;
                const float bia = bias[n0 + p * 64 + lc];
#pragma unroll
                for (int mi = 0; mi < 4; ++mi)
#pragma unroll
                    for (int r = 0; r < 4; ++r) {
                        const int lr = wr * 64 + mi * 16 + quad * 4 + r;
                        float v = acc[mi][ni][r] + bia;
                        if (EPI == 2) v = fmaxf(v, 0.f);
                        lflat[lr * 64 + (lc ^ ((lr & 7) << 3))] = f2bf(v);
                    }
            }
        }
        __syncthreads();
#pragma unroll
        for (int i = 0; i < 4; ++i) {
            const int chunk = i * 256 + t;   // 1024 chunks of short8
            const int row = chunk >> 3;
            const int c8 = (chunk & 7) * 8;
            const int gr = m0 + row;
            if (gr < M) {
                const short8 v8 =
                    *(const short8*)&lflat[row * 64 + (c8 ^ ((row & 7) << 3))];
                const int gcl = n0 + p * 64 + c8;
                if (EPI == 5) {
                    const int b = gr / LQn, s = gr - b * LQn;
                    const int hh = gcl >> 5, dd = gcl & 31;
                    *(short8*)&((short*)C)[(((size_t)b * 8 + hh) * LQn + s) * 32 + dd] = v8;
                } else {
                    *(short8*)&((short*)C)[(size_t)gr * ldc + gcl] = v8;
                }
            }
        }
        __syncthreads();
    }
}

// ---------------------------------------------------------------------------
// 512-thread 128x256-tile GEMM with fused row-LayerNorm epilogue.
// EPI 0: output = bf16 (bounce epilogue). EPI 1: output = fp32 d_out.
// resbf: residual dtype (1 = bf16, 0 = fp32). ldb = K, ldc = 256.
// ---------------------------------------------------------------------------
template <int EPI>
__global__ __launch_bounds__(512) void gemm_ln(const short* __restrict__ Ab,
                                               const short* __restrict__ BT,
                                               const float* __restrict__ bias,
                                               const void* __restrict__ resid,
                                               void* __restrict__ out,
                                               const float* __restrict__ g,
                                               const float* __restrict__ be,
                                               int M, int K, int resbf) {
    const int t = threadIdx.x;
    const int m0 = blockIdx.x * 128;
    const int wid = t >> 6, lane = t & 63;
    const int wr = wid >> 2, wc = wid & 3;
    const int quad = lane >> 4, l16 = lane & 15;

    __shared__ short lA[2][128 * 32];
    __shared__ short lB[2][256 * 32];
    __shared__ float2 part[128][4];
    __shared__ float2 stats[128];

    f32x4 acc[4][4];
#pragma unroll
    for (int i = 0; i < 4; ++i)
#pragma unroll
        for (int j = 0; j < 4; ++j) acc[i][j] = (f32x4){0.f, 0.f, 0.f, 0.f};

    const int ga_row = wid * 16 + (lane >> 2);
    const int gb_row = wid * 32 + (lane >> 2);
    const int gcol8 = (lane & 3) * 8;
    auto stage = [&](int buf, int k0) {
        GLOAD16(Ab + (size_t)(m0 + ga_row) * K + k0 + gcol8,
                &lA[buf][(wid * 16) * 32]);
        GLOAD16(BT + (size_t)gb_row * K + k0 + gcol8,
                &lB[buf][(wid * 32) * 32]);
        GLOAD16(BT + (size_t)(gb_row + 16) * K + k0 + gcol8,
                &lB[buf][(wid * 32 + 16) * 32]);
    };
    stage(0, 0);
    __syncthreads();
    int cur = 0;
    for (int k0 = 0; k0 < K; k0 += 32) {
        if (k0 + 32 < K) stage(cur ^ 1, k0 + 32);
        short8 af[4], bfr[4];
#pragma unroll
        for (int mi = 0; mi < 4; ++mi)
            af[mi] = *(const short8*)&lA[cur][(wr * 64 + mi * 16 + l16) * 32 + quad * 8];
#pragma unroll
        for (int ni = 0; ni < 4; ++ni)
            bfr[ni] = *(const short8*)&lB[cur][(wc * 64 + ni * 16 + l16) * 32 + quad * 8];
#pragma unroll
        for (int mi = 0; mi < 4; ++mi)
#pragma unroll
            for (int ni = 0; ni < 4; ++ni)
                acc[mi][ni] = __builtin_amdgcn_mfma_f32_16x16x32_bf16(
                    af[mi], bfr[ni], acc[mi][ni], 0, 0, 0);
        __syncthreads();
        cur ^= 1;
    }

    float biasv[4], gv[4], bev[4];
    int gcs[4];
#pragma unroll
    for (int ni = 0; ni < 4; ++ni) {
        gcs[ni] = wc * 64 + ni * 16 + l16;
        biasv[ni] = bias[gcs[ni]];
        gv[ni] = g[gcs[ni]];
        bev[ni] = be[gcs[ni]];
    }
#pragma unroll
    for (int mi = 0; mi < 4; ++mi) {
#pragma unroll
        for (int r = 0; r < 4; ++r) {
            const int lr = wr * 64 + mi * 16 + quad * 4 + r;
            const int gr = m0 + lr;
            const bool ok = (gr < M);
            float s1 = 0.f, s2 = 0.f;
#pragma unroll
            for (int ni = 0; ni < 4; ++ni) {
                float v = acc[mi][ni][r] + biasv[ni];
                if (ok) {
                    if (resbf)
                        v += bf2f(((const short*)resid)[(size_t)gr * 256 + gcs[ni]]);
                    else
                        v += ((const float*)resid)[(size_t)gr * 256 + gcs[ni]];
                }
                acc[mi][ni][r] = v;
                s1 += v;
                s2 += v * v;
            }
#pragma unroll
            for (int o = 1; o < 16; o <<= 1) {
                s1 += __shfl_xor(s1, o);
                s2 += __shfl_xor(s2, o);
            }
            if (l16 == 0) part[lr][wc] = make_float2(s1, s2);
        }
    }
    __syncthreads();
    if (t < 128) {
        float s1 = 0.f, s2 = 0.f;
#pragma unroll
        for (int w = 0; w < 4; ++w) {
            const float2 p = part[t][w];
            s1 += p.x;
            s2 += p.y;
        }
        const float mean = s1 * (1.0f / 256.0f);
        const float var = s2 * (1.0f / 256.0f) - mean * mean;
        stats[t] = make_float2(mean, rsqrtf(var + 1e-5f));
    }
    __syncthreads();

    if (EPI == 0) {
        // bf16 output via LDS bounce: 4 passes of 64 cols
        short* lflat = (short*)lA;  // 8192 shorts = 128 x 64
#pragma unroll
        for (int p = 0; p < 4; ++p) {
            if (wc == p) {
#pragma unroll
                for (int mi = 0; mi < 4; ++mi)
#pragma unroll
                    for (int r = 0; r < 4; ++r) {
                        const int lr = wr * 64 + mi * 16 + quad * 4 + r;
                        const float2 st = stats[lr];
#pragma unroll
                        for (int ni = 0; ni < 4; ++ni) {
                            const int lc = ni * 16 + l16;
                            const float v =
                                (acc[mi][ni][r] - st.x) * st.y * gv[ni] + bev[ni];
                            lflat[lr * 64 + (lc ^ ((lr & 7) << 3))] = f2bf(v);
                        }
                    }
            }
            __syncthreads();
#pragma unroll
            for (int i = 0; i < 2; ++i) {
                const int chunk = i * 512 + t;
                const int row = chunk >> 3;
                const int c8 = (chunk & 7) * 8;
                const int gr = m0 + row;
                if (gr < M) {
                    const short8 v8 =
                        *(const short8*)&lflat[row * 64 + (c8 ^ ((row & 7) << 3))];
                    *(short8*)&((short*)out)[(size_t)gr * 256 + p * 64 + c8] = v8;
                }
            }
            __syncthreads();
        }
    } else {
#pragma unroll
        for (int mi = 0; mi < 4; ++mi) {
#pragma unroll
            for (int r = 0; r < 4; ++r) {
                const int lr = wr * 64 + mi * 16 + quad * 4 + r;
                const int gr = m0 + lr;
                if (gr < M) {
                    const float2 st = stats[lr];
#pragma unroll
                    for (int ni = 0; ni < 4; ++ni) {
                        const float v =
                            (acc[mi][ni][r] - st.x) * st.y * gv[ni] + bev[ni];
                        ((float*)out)[(size_t)gr * 256 + gcs[ni]] = v;
                    }
                }
            }
        }
    }
}

// ---------------------------------------------------------------------------
// MS deformable sampling, head-major value [B][NH][LQ][HD].
// 16 threads per (row, head). 32-bit corner addressing (row offsets reused).
// ---------------------------------------------------------------------------
__global__ __launch_bounds__(256) void sample_k(const short* __restrict__ value,
                                                const short* __restrict__ offaw,
                                                const float* __restrict__ refp,
                                                short* __restrict__ attn,
                                                int nwg) {
    int wg = blockIdx.x;
    {
        const int q = nwg >> 3, r = nwg & 7;
        const int xcd = wg & 7, idx = wg >> 3;
        wg = (xcd < r ? xcd * (q + 1) : r * (q + 1) + (xcd - r) * q) + idx;
    }
    const int tid = threadIdx.x;
    const int grp = wg * 16 + (tid >> 4);
    const int s16 = tid & 15;
    const int l = s16 >> 2, sub = s16 & 3;
    const int row = grp >> 3, h = grp & 7;
    const int b = row / LQn;
    const int L = (l == 0) ? 100 : (l == 1) ? 50 : (l == 2) ? 25 : 13;
    const int O = (l == 0) ? 0 : (l == 1) ? 10000 : (l == 2) ? 12500 : 13125;
    const float Lf = (float)L;

    const short* op = offaw + (size_t)row * 384 + h * 32;
    const short* ap = offaw + (size_t)row * 384 + 256 + h * 16;

    const short4v alog = *(const short4v*)(ap + l * 4);
    float lg[4];
#pragma unroll
    for (int j = 0; j < 4; ++j) lg[j] = bf2f(alog[j]);
    float m = fmaxf(fmaxf(lg[0], lg[1]), fmaxf(lg[2], lg[3]));
    m = fmaxf(m, __shfl_xor(m, 4));
    m = fmaxf(m, __shfl_xor(m, 8));
    float s = 0.f;
#pragma unroll
    for (int j = 0; j < 4; ++j) { lg[j] = __expf(lg[j] - m); s += lg[j]; }
    s += __shfl_xor(s, 4);
    s += __shfl_xor(s, 8);
    const float inv = 1.f / s;

    const float2 rxy = *(const float2*)(refp + (size_t)row * 8 + l * 2);
    const short8 ov = *(const short8*)(op + l * 8);
    const short* vlev = value + ((size_t)(b * 8 + h) * LQn + O) * 32 + sub * 8;

    float acc[8];
#pragma unroll
    for (int j = 0; j < 8; ++j) acc[j] = 0.f;

#pragma unroll 2
    for (int p = 0; p < 4; ++p) {
        const float x = fmaf(rxy.x, Lf, bf2f(ov[p * 2 + 0]) - 0.5f);
        const float y = fmaf(rxy.y, Lf, bf2f(ov[p * 2 + 1]) - 0.5f);
        const float xf = floorf(x), yf = floorf(y);
        const int ix = (int)xf, iy = (int)yf;
        const float fx = x - xf, fy = y - yf;
        const float aw = lg[p] * inv;
        const float vx0 = ((unsigned)ix < (unsigned)L) ? 1.f : 0.f;
        const float vx1 = ((unsigned)(ix + 1) < (unsigned)L) ? 1.f : 0.f;
        const float vy0 = ((unsigned)iy < (unsigned)L) ? 1.f : 0.f;
        const float vy1 = ((unsigned)(iy + 1) < (unsigned)L) ? 1.f : 0.f;
        const float gx0 = (1.f - fx) * aw, gx1 = fx * aw;
        const float w00 = gx0 * (1.f - fy) * vx0 * vy0;
        const float w10 = gx1 * (1.f - fy) * vx1 * vy0;
        const float w01 = gx0 * fy * vx0 * vy1;
        const float w11 = gx1 * fy * vx1 * vy1;
        const int ix0 = min(max(ix, 0), L - 1);
        const int ix1 = min(max(ix + 1, 0), L - 1);
        const int iy0 = min(max(iy, 0), L - 1);
        const int iy1 = min(max(iy + 1, 0), L - 1);
        const int ro0 = iy0 * L, ro1 = iy1 * L;
        const short8 v00 = *(const short8*)(vlev + ((ro0 + ix0) << 5));
        const short8 v10 = *(const short8*)(vlev + ((ro0 + ix1) << 5));
        const short8 v01 = *(const short8*)(vlev + ((ro1 + ix0) << 5));
        const short8 v11 = *(const short8*)(vlev + ((ro1 + ix1) << 5));
#pragma unroll
        for (int j = 0; j < 8; ++j)
            acc[j] += w00 * bf2f(v00[j]) + w10 * bf2f(v10[j]) +
                      w01 * bf2f(v01[j]) + w11 * bf2f(v11[j]);
    }

#pragma unroll
    for (int j = 0; j < 8; ++j) {
        acc[j] += __shfl_xor(acc[j], 4);
        acc[j] += __shfl_xor(acc[j], 8);
    }

    if (l == 0) {
        short8 o;
#pragma unroll
        for (int j = 0; j < 8; ++j) o[j] = f2bf(acc[j]);
        *(short8*)(attn + (size_t)row * 256 + h * 32 + sub * 8) = o;
    }
}

// ---------------------------------------------------------------------------
extern "C" void kernel_launch(void* const* d_in, const int* in_sizes, int n_in,
                              void* d_out, int out_size, void* d_ws, size_t ws_size,
                              hipStream_t stream) {
    (void)in_sizes; (void)n_in; (void)out_size;
    const float* src  = (const float*)d_in[0];
    const float* pos  = (const float*)d_in[1];
    const float* refp = (const float*)d_in[2];
    const float* Wv = (const float*)d_in[5];
    const float* bv = (const float*)d_in[6];
    const float* Ws = (const float*)d_in[7];
    const float* bs = (const float*)d_in[8];
    const float* Wa = (const float*)d_in[9];
    const float* ba = (const float*)d_in[10];
    const float* Wo = (const float*)d_in[11];
    const float* bo = (const float*)d_in[12];
    const float* W1 = (const float*)d_in[13];
    const float* b1 = (const float*)d_in[14];
    const float* W2 = (const float*)d_in[15];
    const float* b2 = (const float*)d_in[16];
    const float* g1 = (const float*)d_in[17];
    const float* be1 = (const float*)d_in[18];
    const float* g2 = (const float*)d_in[19];
    const float* be2 = (const float*)d_in[20];

    char* ws = (char*)d_ws;
    size_t off = 0;
    auto take = [&](size_t bytes) {
        char* p = ws + off;
        off += (bytes + 255) & ~(size_t)255;
        return p;
    };
    short* WvT  = (short*)take(256 * 256 * 2);
    short* WsaT = (short*)take(384 * 256 * 2);
    short* WoT  = (short*)take(256 * 256 * 2);
    short* W1T  = (short*)take(1024 * 256 * 2);
    short* W2T  = (short*)take(256 * 1024 * 2);
    float* bsa  = (float*)take(384 * 4);
    short* value_h = (short*)take((size_t)MP * 256 * 2);  // later x_bf
    short* offaw   = (short*)take((size_t)MP * 384 * 2);  // later h part 1
    short* attn_bf = (short*)take((size_t)MP * 256 * 2);  // q_bf / attn / h part 2
    // base total ~96.9 MB; optional persistent src_bf below

    short* src_bf;
    int resbf_g4;
    if (off + (size_t)MP * 256 * 2 <= ws_size) {
        src_bf = (short*)take((size_t)MP * 256 * 2);  // persistent; G4 resid bf16
        resbf_g4 = 1;
    } else {
        src_bf = offaw;  // transient (G2 overwrites after G1); G4 resid fp32
        resbf_g4 = 0;
    }

    short* q_bf = attn_bf;
    short* x_bf = value_h;
    short* h    = offaw;
    float* z    = (float*)d_out;

    prep_all<<<9593, 256, 0, stream>>>(Wv, Ws, Wa, Wo, W1, W2, bs, ba, src, pos,
                                       WvT, WsaT, WoT, W1T, W2T, bsa, q_bf,
                                       src_bf);
    // G1: value (head-major) = src_bf @ WvT + bv   (NT=2, 832 blocks)
    gemm_bt<5, 2><<<832, 256, 0, stream>>>(
        src_bf, WvT, bv, value_h, MREAL, 256, 256, 256, 256);
    // G2: offaw = q_bf @ WsaT + bsa                (NT=3, 1248 blocks)
    gemm_bt<1, 3><<<1248, 256, 0, stream>>>(
        q_bf, WsaT, bsa, offaw, MREAL, 256, 384, 256, 384);
    // Deformable sampling
    {
        const int nwg = (MREAL * 8) / 16;  // 26588 blocks
        sample_k<<<nwg, 256, 0, stream>>>(value_h, offaw, refp, attn_bf, nwg);
    }
    // G4 + LN1 fused: x_bf = LN(resid + attn @ WoT + bo)
    gemm_ln<0><<<MT, 512, 0, stream>>>(attn_bf, WoT, bo,
                                       resbf_g4 ? (const void*)src_bf
                                                : (const void*)src,
                                       x_bf, g1, be1, MREAL, 256, resbf_g4);
    // FFN over two M-halves; G6 + LN2 fused
    for (int half = 0; half < 2; ++half) {
        const size_t ro = (size_t)half * MHALF;
        gemm_bt<2, 8><<<1664, 256, 0, stream>>>(
            x_bf + ro * 256, W1T, b1, h, MHALF, 256, 1024, 256, 1024);
        gemm_ln<1><<<MTH, 512, 0, stream>>>(h, W2T, b2, x_bf + ro * 256,
                                            z + ro * 256, g2, be2, MHALF, 1024,
                                            1);
    }
}